// Round 10
// baseline (1254.269 us; speedup 1.0000x reference)
//
#include <hip/hip_runtime.h>

#define NN 50000
#define EE 500000
#define LL 4

typedef unsigned short u16;
typedef unsigned int u32;

__device__ __forceinline__ float bfc(u16 u) { return __uint_as_float(((u32)u) << 16); }
__device__ __forceinline__ u16 f2bf(float f) {
    u32 u = __float_as_uint(f);
    return (u16)((u + 0x7fffu + ((u >> 16) & 1u)) >> 16);
}
__device__ __forceinline__ float lanebc(float v, int l) {
    return __int_as_float(__builtin_amdgcn_readlane(__float_as_int(v), l));
}
__device__ __forceinline__ void unpack2(u32 w, float& lo, float& hi) {
    lo = __uint_as_float(w << 16);
    hi = __uint_as_float(w & 0xffff0000u);
}

// ---- init: x state (bf16 Xh if big, fp32 Xf if small); zero deg/cursor ----
__global__ __launch_bounds__(256) void k_init(const float* __restrict__ x, float* __restrict__ Xf,
                                              u16* __restrict__ Xh, int big,
                                              int* __restrict__ deg, int* __restrict__ cursor) {
    for (int i = blockIdx.x * 256 + threadIdx.x; i < NN * 64; i += gridDim.x * 256) {
        if (big) Xh[i] = f2bf(x[i]);
        else Xf[i] = x[i];
    }
    for (int i = blockIdx.x * 256 + threadIdx.x; i < NN; i += gridDim.x * 256) {
        deg[i] = 0;
        cursor[i] = 0;
    }
}

// ---- phi[l,b,:] = relu(Lambda[b] @ We1[l] + be1[l]) ----
__global__ __launch_bounds__(128) void k_phi(const float* __restrict__ Lam, const float* __restrict__ We1,
                                             const float* __restrict__ be1, float* __restrict__ phiA) {
    int l = blockIdx.x >> 5, b = blockIdx.x & 31, j = threadIdx.x;
    float acc = be1[l * 128 + j];
    for (int q = 0; q < 8; q++)
        acc = fmaf(Lam[b * 8 + q], We1[l * 1024 + q * 128 + j], acc);
    phiA[l * 4096 + b * 128 + j] = fmaxf(acc, 0.f);
}

// ---- M[l] = Wee[l] @ Wg[l] (16x16 per layer) ----
__global__ __launch_bounds__(256) void k_small(const float* __restrict__ Wee, const float* __restrict__ Wg,
                                               float* __restrict__ MA) {
    int l = blockIdx.x, t = threadIdx.x;
    int k = t >> 4, h = t & 15;
    float m = 0.f;
    for (int f = 0; f < 64; f++)
        m = fmaf(Wee[l * 1024 + k * 64 + f], Wg[l * 1024 + f * 16 + h], m);
    MA[l * 256 + t] = m;
}

// ---- CSR build ----
__global__ __launch_bounds__(256) void k_hist(const int* __restrict__ ei, int* __restrict__ deg) {
    int e = blockIdx.x * 256 + threadIdx.x;
    if (e < EE) {
        int d = ei[EE + e];
        if (d >= 0 && d < NN) atomicAdd(&deg[d], 1);
    }
}

__global__ __launch_bounds__(256) void k_scan1(const int* __restrict__ deg, int* __restrict__ rowptr,
                                               int* __restrict__ bsum) {
    __shared__ int tmp[256];
    int t = threadIdx.x, i = blockIdx.x * 256 + t;
    int v = (i < NN) ? deg[i] : 0;
    tmp[t] = v;
    __syncthreads();
    for (int off = 1; off < 256; off <<= 1) {
        int a = (t >= off) ? tmp[t - off] : 0;
        __syncthreads();
        tmp[t] += a;
        __syncthreads();
    }
    if (i < NN) rowptr[i] = tmp[t] - v;
    if (t == 255) bsum[blockIdx.x] = tmp[255];
}

__global__ __launch_bounds__(256) void k_scan2(const int* __restrict__ bsum, int* __restrict__ boff,
                                               int* __restrict__ rowptr, int nb) {
    __shared__ int tmp[256];
    int t = threadIdx.x;
    int v = (t < nb) ? bsum[t] : 0;
    tmp[t] = v;
    __syncthreads();
    for (int off = 1; off < 256; off <<= 1) {
        int a = (t >= off) ? tmp[t - off] : 0;
        __syncthreads();
        tmp[t] += a;
        __syncthreads();
    }
    if (t < nb) boff[t] = tmp[t] - v;
    if (t == 255) rowptr[NN] = tmp[255];
}

__global__ __launch_bounds__(256) void k_scan3(int* __restrict__ rowptr, const int* __restrict__ boff) {
    int i = blockIdx.x * 256 + threadIdx.x;
    if (i < NN) rowptr[i] += boff[blockIdx.x];
}

__global__ __launch_bounds__(256) void k_scatter(const int* __restrict__ ei, const int* __restrict__ batch,
                                                 const int* __restrict__ rowptr, int* __restrict__ cursor,
                                                 u32* __restrict__ sb, int* __restrict__ eeo) {
    int e = blockIdx.x * 256 + threadIdx.x;
    if (e < EE) {
        int s = ei[e], d = ei[EE + e];
        if (s < 0) s = 0; if (s >= NN) s = NN - 1;
        if (d < 0) d = 0; if (d >= NN) d = NN - 1;
        int pos = rowptr[d] + atomicAdd(&cursor[d], 1);
        if (pos >= 0 && pos < EE) {
            sb[pos] = (u32)s | ((u32)(batch[s] & 31) << 16);
            eeo[pos] = e;
        }
    }
}

// ---- permute edge_attr into CSR order, bf16, float4-wide ----
__global__ __launch_bounds__(256) void k_perm(const float* __restrict__ eat, const int* __restrict__ eeo,
                                              u16* __restrict__ eatp) {
    const float4* e4 = reinterpret_cast<const float4*>(eat);
    ushort4* o4 = reinterpret_cast<ushort4*>(eatp);
    for (long long i = (long long)blockIdx.x * 256 + threadIdx.x; i < (long long)EE * 16;
         i += (long long)gridDim.x * 256) {
        int idx = (int)(i >> 4), cc = (int)(i & 15);
        int e = eeo[idx];
        float4 v = e4[(size_t)e * 16 + cc];
        ushort4 o;
        o.x = f2bf(v.x); o.y = f2bf(v.y); o.z = f2bf(v.z); o.w = f2bf(v.w);
        o4[i] = o;
    }
}

// ---- ALL layers: EAGp4[l][idx][h] = pack( (eatp[idx]+bee[l])@Wg[l] + bg[l] ) ----
__global__ __launch_bounds__(256) void k_eag_all(const u16* __restrict__ eatp, const float* __restrict__ Wg,
                                                 const float* __restrict__ bee, const float* __restrict__ bg,
                                                 u32* __restrict__ EAGp4) {
    __shared__ float sWg[4096];     // 4 layers x 64 x 16
    __shared__ float scv[64];       // 4 layers x 16
    __shared__ u32 srow[256][33];
    const int t = threadIdx.x;
    for (int i = t; i < 4096; i += 256) sWg[i] = Wg[i];
    __syncthreads();
    if (t < 64) {
        const int l = t >> 4, h = t & 15;
        float c = bg[l * 16 + h];
        for (int j = 0; j < 64; j++) c = fmaf(bee[l * 64 + j], sWg[l * 1024 + j * 16 + h], c);
        scv[t] = c;
    }
    const int base = blockIdx.x * 256;
    const u32* eat32 = (const u32*)eatp;
    for (int i = t; i < 256 * 32; i += 256) {
        int r = i >> 5, c = i & 31;
        int idx = base + r;
        srow[r][c] = (idx < EE) ? eat32[(size_t)idx * 32 + c] : 0u;
    }
    __syncthreads();
    const int idx = base + t;
    if (idx >= EE) return;
#pragma unroll
    for (int l = 0; l < LL; l++) {
        const float* wl = &sWg[l * 1024];
        float acc[16];
#pragma unroll
        for (int h = 0; h < 16; h++) acc[h] = scv[l * 16 + h];
#pragma unroll
        for (int c = 0; c < 32; c++) {
            float a0, a1;
            unpack2(srow[t][c], a0, a1);
            const float* w0 = &wl[(2 * c) * 16];
#pragma unroll
            for (int h = 0; h < 16; h++) acc[h] = fmaf(a0, w0[h], fmaf(a1, w0[16 + h], acc[h]));
        }
        u32 w[8];
#pragma unroll
        for (int h = 0; h < 8; h++) w[h] = (u32)f2bf(acc[h]) | ((u32)f2bf(acc[8 + h]) << 16);
        uint4* op = reinterpret_cast<uint4*>(EAGp4 + (size_t)l * EE * 8 + (size_t)idx * 8);
        op[0] = make_uint4(w[0], w[1], w[2], w[3]);
        op[1] = make_uint4(w[4], w[5], w[6], w[7]);
    }
}

// ---- per-layer EAG (big-path fallback when ws can't hold 4 layers) ----
__global__ __launch_bounds__(256) void k_eag2(const u16* __restrict__ eatp, const float* __restrict__ WgL,
                                              const float* __restrict__ beeL, const float* __restrict__ bgL,
                                              u32* __restrict__ EAGp) {
    __shared__ float sWg[1024];
    __shared__ float scv[16];
    __shared__ u32 srow[256][33];
    const int t = threadIdx.x;
    for (int i = t; i < 1024; i += 256) sWg[i] = WgL[i];
    __syncthreads();
    if (t < 16) {
        float c = bgL[t];
        for (int j = 0; j < 64; j++) c = fmaf(beeL[j], sWg[j * 16 + t], c);
        scv[t] = c;
    }
    const int base = blockIdx.x * 256;
    const u32* eat32 = (const u32*)eatp;
    for (int i = t; i < 256 * 32; i += 256) {
        int r = i >> 5, c = i & 31;
        int idx = base + r;
        srow[r][c] = (idx < EE) ? eat32[(size_t)idx * 32 + c] : 0u;
    }
    __syncthreads();
    const int idx = base + t;
    if (idx < EE) {
        float acc[16];
#pragma unroll
        for (int h = 0; h < 16; h++) acc[h] = scv[h];
#pragma unroll
        for (int c = 0; c < 32; c++) {
            float a0, a1;
            unpack2(srow[t][c], a0, a1);
            const float* w0 = &sWg[(2 * c) * 16];
#pragma unroll
            for (int h = 0; h < 16; h++) acc[h] = fmaf(a0, w0[h], fmaf(a1, w0[16 + h], acc[h]));
        }
        u32 w[8];
#pragma unroll
        for (int h = 0; h < 8; h++) w[h] = (u32)f2bf(acc[h]) | ((u32)f2bf(acc[8 + h]) << 16);
        uint4* op = reinterpret_cast<uint4*>(EAGp + (size_t)idx * 8);
        op[0] = make_uint4(w[0], w[1], w[2], w[3]);
        op[1] = make_uint4(w[4], w[5], w[6], w[7]);
    }
}

// ==== BIG-path fused edge pass v4: chunked sb preload + QUAD-edge double-buffered
//      pipeline (8 edges in flight), gate via parallel mlo/mhi chains ====
template <int INM, int FIN>
__global__ __launch_bounds__(256) void k_edge4(const float2* __restrict__ Z2,
                                               const float* __restrict__ pe,
                                               const u16* __restrict__ Xh,
                                               const u16* __restrict__ eatp, const u32* __restrict__ EAGp,
                                               const int* __restrict__ rowptr, const u32* __restrict__ sb,
                                               const float* __restrict__ phiL, const float* __restrict__ WeeL,
                                               const float* __restrict__ beeL, const float* __restrict__ ML,
                                               const float* __restrict__ WpL, const float* __restrict__ bpL,
                                               float* __restrict__ Hf, float2* __restrict__ Z2O,
                                               float* __restrict__ outz,
                                               double* __restrict__ stats) {
    __shared__ float sphi[4096];
    __shared__ float sWp[256];
    __shared__ float sbp[16];
    if (blockIdx.x == 0) stats[threadIdx.x] = 0.0;
    for (int t = threadIdx.x; t < 4096; t += 256) sphi[t] = phiL[t];
    if (threadIdx.x < 256) sWp[threadIdx.x] = WpL[threadIdx.x];
    if (threadIdx.x < 16) sbp[threadIdx.x] = bpL[threadIdx.x];
    const int lane = threadIdx.x & 63;
    const int wid = threadIdx.x >> 6;
    const int hlo = lane >> 3;
    const int pp = lane & 7;
    float wee[16], mlo[16], mhi[16];
#pragma unroll
    for (int k = 0; k < 16; k++) {
        wee[k] = WeeL[k * 64 + lane];
        mlo[k] = ML[k * 16 + hlo];
        mhi[k] = ML[k * 16 + 8 + hlo];
    }
    const float beev = beeL[lane];
    __syncthreads();

    struct Ed { u32 w; float z0, z1, xs, ea, gl, gh; };

    for (int n = blockIdx.x * 4 + wid; n < NN; n += gridDim.x * 4) {
        float zd0, zd1;
        if (INM == 0) { zd0 = zd1 = pe[n * 8 + pp]; }
        else { float2 t = Z2[n * 64 + lane]; zd0 = t.x; zd1 = t.y; }
        float accx = bfc(Xh[n * 64 + lane]);
        float az0 = zd0, az1 = zd1;
        int i0 = rowptr[n], i1 = rowptr[n + 1];
        if (i0 < 0) i0 = 0;
        if (i1 > EE) i1 = EE;
        for (int c = i0; c < i1; c += 64) {
            const int ce = (c + 64 < i1) ? c + 64 : i1;
            const int m = ce - c;         // 1..64 edges this chunk (wave-uniform)
            const int mL = m - 1;
            int ci = c + lane; if (ci > i1 - 1) ci = i1 - 1;
            const u32 svec = sb[ci];      // whole chunk's (src|batch) in one load

            auto EF = [&](Ed& R, int kk) {
                if (kk > mL) kk = mL;
                R.w = (u32)__builtin_amdgcn_readlane((int)svec, kk);
                const int s_ = (int)(R.w & 0xffffu);
                if (INM == 0) { R.z0 = R.z1 = pe[s_ * 8 + pp]; }
                else { float2 t_ = Z2[s_ * 64 + lane]; R.z0 = t_.x; R.z1 = t_.y; }
                R.xs = bfc(Xh[s_ * 64 + lane]);
                const size_t ge_ = (size_t)(c + kk);
                R.ea = bfc(eatp[ge_ * 64 + lane]);
                unpack2(EAGp[ge_ * 8 + hlo], R.gl, R.gh);
            };
            auto EC = [&](const Ed& R, float msk) {
                const int b_ = (int)((R.w >> 16) & 31u);
                float p0 = sphi[b_ * 128 + lane] * R.z0 * zd0;
                float p1 = sphi[b_ * 128 + 64 + lane] * R.z1 * zd1;
                p0 += __shfl_xor(p0, 1); p1 += __shfl_xor(p1, 1);
                p0 += __shfl_xor(p0, 2); p1 += __shfl_xor(p1, 2);
                p0 += __shfl_xor(p0, 4); p1 += __shfl_xor(p1, 4);
                float eaA = 0.f, eaB = 0.f, gA = R.gl, gB = 0.f, hA = R.gh, hB = 0.f;
#pragma unroll
                for (int k_ = 0; k_ < 8; k_++) {
                    const float e_ = lanebc(p0, k_ << 3);
                    eaA = fmaf(e_, wee[k_], eaA);
                    gA = fmaf(e_, mlo[k_], gA);
                    hA = fmaf(e_, mhi[k_], hA);
                }
#pragma unroll
                for (int k_ = 0; k_ < 8; k_++) {
                    const float e_ = lanebc(p1, k_ << 3);
                    eaB = fmaf(e_, wee[8 + k_], eaB);
                    gB = fmaf(e_, mlo[8 + k_], gB);
                    hB = fmaf(e_, mhi[8 + k_], hB);
                }
                const float ea_ = beev + R.ea + eaA + eaB;
                accx = fmaf(msk, fmaxf(0.f, R.xs + ea_), accx);
                az0 = fmaf(msk, fmaxf(0.f, R.z0 + fmaxf(gA + gB, 0.f)), az0);
                az1 = fmaf(msk, fmaxf(0.f, R.z1 + fmaxf(hA + hB, 0.f)), az1);
            };

            Ed X0, X1, X2, X3, Y0, Y1, Y2, Y3;
            EF(X0, 0); EF(X1, 1); EF(X2, 2); EF(X3, 3);
            for (int k = 0; k < m; k += 8) {
                EF(Y0, k + 4); EF(Y1, k + 5); EF(Y2, k + 6); EF(Y3, k + 7);
                EC(X0, 1.f);
                EC(X1, (k + 1 < m) ? 1.f : 0.f);
                EC(X2, (k + 2 < m) ? 1.f : 0.f);
                EC(X3, (k + 3 < m) ? 1.f : 0.f);
                if (k + 4 < m) {   // wave-uniform branch
                    EF(X0, k + 8); EF(X1, k + 9); EF(X2, k + 10); EF(X3, k + 11);
                    EC(Y0, 1.f);
                    EC(Y1, (k + 5 < m) ? 1.f : 0.f);
                    EC(Y2, (k + 6 < m) ? 1.f : 0.f);
                    EC(Y3, (k + 7 < m) ? 1.f : 0.f);
                }
            }
        }
        Hf[n * 64 + lane] = accx;
        float r0 = sbp[hlo], r1 = sbp[8 + hlo];
#pragma unroll
        for (int h = 0; h < 8; h++) {
            const float v = __shfl(az0, (h << 3) + pp);
            r0 = fmaf(v, sWp[h * 16 + hlo], r0);
            r1 = fmaf(v, sWp[h * 16 + 8 + hlo], r1);
        }
#pragma unroll
        for (int h = 0; h < 8; h++) {
            const float v = __shfl(az1, (h << 3) + pp);
            r0 = fmaf(v, sWp[(8 + h) * 16 + hlo], r0);
            r1 = fmaf(v, sWp[(8 + h) * 16 + 8 + hlo], r1);
        }
        if (FIN) {
            outz[n * 128 + lane] = r0;
            outz[n * 128 + 64 + lane] = r1;
        } else {
            Z2O[n * 64 + lane] = make_float2(r0, r1);
        }
    }
}

// ==== SMALL-path fused edge pass (round-4, proven fallback) ====
template <int INM>
__global__ __launch_bounds__(256) void k_edge_s(const float* __restrict__ Zf,
                                                const float* __restrict__ pe,
                                                const float* __restrict__ Xf, const float* __restrict__ eat,
                                                const int* __restrict__ rowptr, const u32* __restrict__ sb,
                                                const int* __restrict__ eeo,
                                                const float* __restrict__ phiL, const float* __restrict__ WeeL,
                                                const float* __restrict__ beeL,
                                                const float* __restrict__ WgL, const float* __restrict__ bgL,
                                                const float* __restrict__ WpL, const float* __restrict__ bpL,
                                                float* __restrict__ Hf, float* __restrict__ ZfO,
                                                double* __restrict__ stats) {
    __shared__ float sphi[32 * 128];
    __shared__ float sWp[256];
    __shared__ float sbp[16];
    if (blockIdx.x == 0) stats[threadIdx.x] = 0.0;
    for (int t = threadIdx.x; t < 4096; t += 256) sphi[t] = phiL[t];
    if (threadIdx.x < 256) sWp[threadIdx.x] = WpL[threadIdx.x];
    if (threadIdx.x < 16) sbp[threadIdx.x] = bpL[threadIdx.x];
    const int lane = threadIdx.x & 63;
    const int wid = threadIdx.x >> 6;
    const int hlo = lane >> 3;
    const int pp = lane & 7;
    const int h16 = lane & 15;
    const int g16 = lane & 48;
    float wee[16], wgr[16];
#pragma unroll
    for (int k = 0; k < 16; k++) {
        wee[k] = WeeL[k * 64 + lane];
        wgr[k] = WgL[(g16 + k) * 16 + h16];
    }
    const float beev = beeL[lane];
    const float bgr = bgL[h16];
    __syncthreads();
    for (int n = blockIdx.x * 4 + wid; n < NN; n += gridDim.x * 4) {
        float zd0, zd1;
        if (INM == 0) { zd0 = zd1 = pe[n * 8 + pp]; }
        else { zd0 = Zf[n * 128 + lane]; zd1 = Zf[n * 128 + 64 + lane]; }
        float accx = Xf[n * 64 + lane];
        float az0 = zd0, az1 = zd1;
        int i0 = rowptr[n], i1 = rowptr[n + 1];
        if (i0 < 0) i0 = 0;
        if (i1 > EE) i1 = EE;
        for (int idx = i0; idx < i1; ++idx) {
            const u32 w = sb[idx];
            const int s = w & 0xffff;
            const int b = (w >> 16) & 31;
            int e = eeo[idx];
            e = (e < 0) ? 0 : ((e >= EE) ? EE - 1 : e);
            float zs0, zs1;
            if (INM == 0) { zs0 = zs1 = pe[s * 8 + pp]; }
            else { zs0 = Zf[s * 128 + lane]; zs1 = Zf[s * 128 + 64 + lane]; }
            float p0 = sphi[b * 128 + lane] * zs0 * zd0;
            float p1 = sphi[b * 128 + 64 + lane] * zs1 * zd1;
            p0 += __shfl_xor(p0, 1); p1 += __shfl_xor(p1, 1);
            p0 += __shfl_xor(p0, 2); p1 += __shfl_xor(p1, 2);
            p0 += __shfl_xor(p0, 4); p1 += __shfl_xor(p1, 4);
            float ea = beev + eat[(size_t)e * 64 + lane];
#pragma unroll
            for (int k = 0; k < 8; k++) ea = fmaf(lanebc(p0, k << 3), wee[k], ea);
#pragma unroll
            for (int k = 0; k < 8; k++) ea = fmaf(lanebc(p1, k << 3), wee[8 + k], ea);
            float gp = 0.f;
#pragma unroll
            for (int i = 0; i < 16; i++) gp = fmaf(__shfl(ea, g16 + i), wgr[i], gp);
            gp += __shfl_xor(gp, 16);
            gp += __shfl_xor(gp, 32);
            const float gv = fmaxf(gp + bgr, 0.f);
            const float glo = __shfl(gv, hlo);
            const float ghi = __shfl(gv, 8 + hlo);
            const float xs = Xf[s * 64 + lane];
            accx += fmaxf(0.f, xs + ea);
            az0 += fmaxf(0.f, zs0 + glo);
            az1 += fmaxf(0.f, zs1 + ghi);
        }
        Hf[n * 64 + lane] = accx;
        float r0 = sbp[hlo], r1 = sbp[8 + hlo];
#pragma unroll
        for (int h = 0; h < 8; h++) {
            const float v = __shfl(az0, (h << 3) + pp);
            r0 = fmaf(v, sWp[h * 16 + hlo], r0);
            r1 = fmaf(v, sWp[h * 16 + 8 + hlo], r1);
        }
#pragma unroll
        for (int h = 0; h < 8; h++) {
            const float v = __shfl(az1, (h << 3) + pp);
            r0 = fmaf(v, sWp[(8 + h) * 16 + hlo], r0);
            r1 = fmaf(v, sWp[(8 + h) * 16 + 8 + hlo], r1);
        }
        ZfO[n * 128 + lane] = r0;
        ZfO[n * 128 + 64 + lane] = r1;
    }
}

// ---- t = h @ W1 + b1 (in-place on Hf), fused BN1 stats ----
__global__ __launch_bounds__(256) void k_gemm1(float* Buf, const float* __restrict__ WL,
                                               const float* __restrict__ bL,
                                               double* __restrict__ sum, double* __restrict__ sq) {
    __shared__ float sW[4096];
    __shared__ double red[512];
    for (int t = threadIdx.x; t < 4096; t += 256) sW[t] = WL[t];
    const int lane = threadIdx.x & 63, wid = threadIdx.x >> 6;
    const float bv = bL[lane];
    __syncthreads();
    double s = 0.0, q = 0.0;
    for (int n = blockIdx.x * 4 + wid; n < NN; n += gridDim.x * 4) {
        const float h = Buf[n * 64 + lane];
        float a0 = bv, a1 = 0.f;
#pragma unroll
        for (int k = 0; k < 32; k++) a0 = fmaf(lanebc(h, k), sW[k * 64 + lane], a0);
#pragma unroll
        for (int k = 32; k < 64; k++) a1 = fmaf(lanebc(h, k), sW[k * 64 + lane], a1);
        const float acc = a0 + a1;
        Buf[n * 64 + lane] = acc;
        s += (double)acc;
        q += (double)acc * (double)acc;
    }
    red[threadIdx.x] = s;
    red[256 + threadIdx.x] = q;
    __syncthreads();
    if (threadIdx.x < 64) {
        s = red[threadIdx.x] + red[threadIdx.x + 64] + red[threadIdx.x + 128] + red[threadIdx.x + 192];
        q = red[256 + threadIdx.x] + red[320 + threadIdx.x] + red[384 + threadIdx.x] + red[448 + threadIdx.x];
        atomicAdd(&sum[lane], s);
        atomicAdd(&sq[lane], q);
    }
}

// ---- h2 = relu(BN1(t)) @ W2 + b2 (in-place on Hf), fused BN2 stats ----
__global__ __launch_bounds__(256) void k_gemm2(float* Buf, const float* __restrict__ WL,
                                               const float* __restrict__ bL,
                                               const float* __restrict__ gL, const float* __restrict__ betaL,
                                               const double* __restrict__ s1, const double* __restrict__ q1,
                                               double* __restrict__ sum, double* __restrict__ sq) {
    __shared__ float sW[4096];
    __shared__ double red[512];
    for (int t = threadIdx.x; t < 4096; t += 256) sW[t] = WL[t];
    const int lane = threadIdx.x & 63, wid = threadIdx.x >> 6;
    const float bv = bL[lane];
    const double mu = s1[lane] * (1.0 / NN);
    const double var = q1[lane] * (1.0 / NN) - mu * mu;
    const float inv = rsqrtf(fmaxf((float)var, 0.f) + 1e-5f);
    const float gm = gL[lane] * inv;
    const float ga = betaL[lane] - (float)mu * gm;
    __syncthreads();
    double s = 0.0, q = 0.0;
    for (int n = blockIdx.x * 4 + wid; n < NN; n += gridDim.x * 4) {
        const float v = Buf[n * 64 + lane];
        const float r = fmaxf(fmaf(v, gm, ga), 0.f);
        float a0 = bv, a1 = 0.f;
#pragma unroll
        for (int k = 0; k < 32; k++) a0 = fmaf(lanebc(r, k), sW[k * 64 + lane], a0);
#pragma unroll
        for (int k = 32; k < 64; k++) a1 = fmaf(lanebc(r, k), sW[k * 64 + lane], a1);
        const float acc = a0 + a1;
        Buf[n * 64 + lane] = acc;
        s += (double)acc;
        q += (double)acc * (double)acc;
    }
    red[threadIdx.x] = s;
    red[256 + threadIdx.x] = q;
    __syncthreads();
    if (threadIdx.x < 64) {
        s = red[threadIdx.x] + red[threadIdx.x + 64] + red[threadIdx.x + 128] + red[threadIdx.x + 192];
        q = red[256 + threadIdx.x] + red[320 + threadIdx.x] + red[384 + threadIdx.x] + red[448 + threadIdx.x];
        atomicAdd(&sum[lane], s);
        atomicAdd(&sq[lane], q);
    }
}

// ---- big path: x = BN2(h2); layers 0-2 -> bf16 Xh with relu; layer 3 -> fp32 out ----
__global__ __launch_bounds__(256) void k_bnout2(const float* __restrict__ In, u16* __restrict__ Xh,
                                                float* __restrict__ outx,
                                                const double* __restrict__ s2, const double* __restrict__ q2,
                                                const float* __restrict__ gL, const float* __restrict__ bL,
                                                int last) {
    int i = blockIdx.x * 256 + threadIdx.x;
    const int f = i & 63;
    const double mu = s2[f] * (1.0 / NN);
    const double var = q2[f] * (1.0 / NN) - mu * mu;
    const float inv = rsqrtf(fmaxf((float)var, 0.f) + 1e-5f);
    const float gm = gL[f] * inv;
    const float ga = bL[f] - (float)mu * gm;
    for (; i < NN * 64; i += gridDim.x * 256) {
        float o = fmaf(In[i], gm, ga);
        if (last) {
            outx[i] = o;
        } else {
            o = fmaxf(o, 0.f);
            Xh[i] = f2bf(o);
        }
    }
}

// ---- small path bnout (fp32 x state) ----
__global__ __launch_bounds__(256) void k_bnout(const float* __restrict__ In, float* __restrict__ Xf,
                                               const double* __restrict__ s2, const double* __restrict__ q2,
                                               const float* __restrict__ gL, const float* __restrict__ bL,
                                               int dorelu) {
    int i = blockIdx.x * 256 + threadIdx.x;
    const int f = i & 63;
    const double mu = s2[f] * (1.0 / NN);
    const double var = q2[f] * (1.0 / NN) - mu * mu;
    const float inv = rsqrtf(fmaxf((float)var, 0.f) + 1e-5f);
    const float gm = gL[f] * inv;
    const float ga = bL[f] - (float)mu * gm;
    for (; i < NN * 64; i += gridDim.x * 256) {
        float o = fmaf(In[i], gm, ga);
        if (dorelu) o = fmaxf(o, 0.f);
        Xf[i] = o;
    }
}

extern "C" void kernel_launch(void* const* d_in, const int* in_sizes, int n_in,
                              void* d_out, int out_size, void* d_ws, size_t ws_size,
                              hipStream_t stream) {
    (void)in_sizes; (void)n_in; (void)out_size;
    const float* x    = (const float*)d_in[0];
    const float* pe   = (const float*)d_in[1];
    const float* Lam  = (const float*)d_in[2];
    const float* eat  = (const float*)d_in[3];
    const int*   ei   = (const int*)d_in[4];
    const int*   batch= (const int*)d_in[5];
    const float* We1  = (const float*)d_in[6];
    const float* be1  = (const float*)d_in[7];
    const float* Wee  = (const float*)d_in[8];
    const float* bee  = (const float*)d_in[9];
    const float* W1   = (const float*)d_in[10];
    const float* b1   = (const float*)d_in[11];
    const float* g1   = (const float*)d_in[12];
    const float* bt1  = (const float*)d_in[13];
    const float* W2   = (const float*)d_in[14];
    const float* b2   = (const float*)d_in[15];
    const float* Wg   = (const float*)d_in[16];
    const float* bg   = (const float*)d_in[17];
    const float* Wp   = (const float*)d_in[18];
    const float* bp   = (const float*)d_in[19];
    const float* gn   = (const float*)d_in[20];
    const float* bnb  = (const float*)d_in[21];

    // output regions
    float* Xf   = (float*)d_out;              // [N,64]
    u16*   Xh   = (u16*)d_out;                // big path: bf16 x state in out-x region
    float* B    = (float*)d_out + 3200000;    // [N,128] z region

    // workspace layout
    float* A    = (float*)d_ws;                 // z plane [N][128] fp32, 25.6 MB
    float* Hf   = A + 6400000;
    float* MA   = Hf + 3200000;
    float* phiA = MA + 1024;
    double* stats = (double*)(phiA + 16384);
    double* s1 = stats, *q1 = stats + 64, *s2 = stats + 128, *q2 = stats + 192;
    int* rowptr = (int*)(stats + 256);
    int* deg    = rowptr + NN + 1;
    int* bsum   = deg + NN;
    int* boff   = bsum + 256;
    int* cursor = boff + 256;
    u32* sb     = (u32*)(cursor + NN);          // EE
    int* eeo    = (int*)(sb + EE);              // EE
    u16* eatp   = (u16*)(eeo + EE);             // EE*64 u16 (64 MB)
    u32* EAGp   = (u32*)(eatp + (size_t)EE * 64); // EE*8 u32 per layer
    const size_t NEED_BIG  = (size_t)((char*)(EAGp + (size_t)EE * 8) - (char*)d_ws);
    const size_t NEED_BIG2 = (size_t)((char*)(EAGp + (size_t)EE * 32) - (char*)d_ws);
    const bool big2 = (ws_size >= NEED_BIG2);
    const bool big  = (ws_size >= NEED_BIG);

    float2* A2 = (float2*)A;
    float2* B2 = (float2*)B;

    const int NB_N = (NN + 255) / 256;
    const int NB_E = (EE + 255) / 256;

    k_init<<<1024, 256, 0, stream>>>(x, Xf, Xh, big ? 1 : 0, deg, cursor);
    k_phi<<<LL * 32, 128, 0, stream>>>(Lam, We1, be1, phiA);
    k_hist<<<NB_E, 256, 0, stream>>>(ei, deg);
    k_scan1<<<NB_N, 256, 0, stream>>>(deg, rowptr, bsum);
    k_scan2<<<1, 256, 0, stream>>>(bsum, boff, rowptr, NB_N);
    k_scan3<<<NB_N, 256, 0, stream>>>(rowptr, boff);
    k_scatter<<<NB_E, 256, 0, stream>>>(ei, batch, rowptr, cursor, sb, eeo);
    if (big) {
        k_small<<<LL, 256, 0, stream>>>(Wee, Wg, MA);
        k_perm<<<4096, 256, 0, stream>>>(eat, eeo, eatp);
        if (big2)
            k_eag_all<<<NB_E, 256, 0, stream>>>(eatp, Wg, bee, bg, EAGp);
    }

    for (int l = 0; l < LL; l++) {
        const float* WeeL = Wee + l * 1024;
        const float* beeL = bee + l * 64;
        const float* WgL  = Wg + l * 1024;
        const float* bgL  = bg + l * 16;
        const float* WpL  = Wp + l * 256;
        const float* bpL  = bp + l * 16;
        const float* phiL = phiA + l * 4096;
        const float* ML   = MA + l * 256;
        if (big) {
            const u32* EAGl = big2 ? (EAGp + (size_t)l * EE * 8) : EAGp;
            if (!big2)
                k_eag2<<<NB_E, 256, 0, stream>>>(eatp, WgL, beeL, bgL, EAGp);
            // z schedule: l0 pe->A2, l1 A2->B2, l2 B2->A2, l3 A2->B(final std layout)
            if (l == 0)
                k_edge4<0, 0><<<6272, 256, 0, stream>>>(A2, pe, Xh, eatp, EAGl, rowptr, sb,
                                                        phiL, WeeL, beeL, ML, WpL, bpL,
                                                        Hf, A2, nullptr, stats);
            else if (l == 1)
                k_edge4<1, 0><<<6272, 256, 0, stream>>>(A2, pe, Xh, eatp, EAGl, rowptr, sb,
                                                        phiL, WeeL, beeL, ML, WpL, bpL,
                                                        Hf, B2, nullptr, stats);
            else if (l == 2)
                k_edge4<1, 0><<<6272, 256, 0, stream>>>(B2, pe, Xh, eatp, EAGl, rowptr, sb,
                                                        phiL, WeeL, beeL, ML, WpL, bpL,
                                                        Hf, A2, nullptr, stats);
            else
                k_edge4<1, 1><<<6272, 256, 0, stream>>>(A2, pe, Xh, eatp, EAGl, rowptr, sb,
                                                        phiL, WeeL, beeL, ML, WpL, bpL,
                                                        Hf, nullptr, B, stats);
        } else {
            const float* Zin  = (l == 2) ? B : A;
            float*       Zout = (l == 1 || l == 3) ? B : A;
            if (l == 0)
                k_edge_s<0><<<2048, 256, 0, stream>>>(nullptr, pe, Xf, eat, rowptr, sb, eeo,
                                                      phiL, WeeL, beeL, WgL, bgL, WpL, bpL,
                                                      Hf, Zout, stats);
            else
                k_edge_s<1><<<2048, 256, 0, stream>>>(Zin, pe, Xf, eat, rowptr, sb, eeo,
                                                      phiL, WeeL, beeL, WgL, bgL, WpL, bpL,
                                                      Hf, Zout, stats);
        }
        k_gemm1<<<512, 256, 0, stream>>>(Hf, W1 + l * 4096, b1 + l * 64, s1, q1);
        k_gemm2<<<512, 256, 0, stream>>>(Hf, W2 + l * 4096, b2 + l * 64,
                                         g1 + l * 64, bt1 + l * 64, s1, q1, s2, q2);
        if (big)
            k_bnout2<<<1024, 256, 0, stream>>>(Hf, Xh, Xf, s2, q2, gn + l * 64, bnb + l * 64,
                                               (l == LL - 1) ? 1 : 0);
        else
            k_bnout<<<1024, 256, 0, stream>>>(Hf, Xf, s2, q2, gn + l * 64, bnb + l * 64,
                                              (l == LL - 1) ? 0 : 1);
    }
}

// Round 11
// 1149.230 us; speedup vs baseline: 1.0914x; 1.0914x over previous
//
#include <hip/hip_runtime.h>

#define NN 50000
#define EE 500000
#define LL 4

typedef unsigned short u16;
typedef unsigned int u32;

__device__ __forceinline__ float bfc(u16 u) { return __uint_as_float(((u32)u) << 16); }
__device__ __forceinline__ u16 f2bf(float f) {
    u32 u = __float_as_uint(f);
    return (u16)((u + 0x7fffu + ((u >> 16) & 1u)) >> 16);
}
__device__ __forceinline__ float lanebc(float v, int l) {
    return __int_as_float(__builtin_amdgcn_readlane(__float_as_int(v), l));
}
__device__ __forceinline__ void unpack2(u32 w, float& lo, float& hi) {
    lo = __uint_as_float(w << 16);
    hi = __uint_as_float(w & 0xffff0000u);
}

// ---- init: x state (bf16 Xh if big, fp32 Xf if small); zero deg/cursor ----
__global__ __launch_bounds__(256) void k_init(const float* __restrict__ x, float* __restrict__ Xf,
                                              u16* __restrict__ Xh, int big,
                                              int* __restrict__ deg, int* __restrict__ cursor) {
    for (int i = blockIdx.x * 256 + threadIdx.x; i < NN * 64; i += gridDim.x * 256) {
        if (big) Xh[i] = f2bf(x[i]);
        else Xf[i] = x[i];
    }
    for (int i = blockIdx.x * 256 + threadIdx.x; i < NN; i += gridDim.x * 256) {
        deg[i] = 0;
        cursor[i] = 0;
    }
}

// ---- phi[l,b,:] = relu(Lambda[b] @ We1[l] + be1[l]) ----
__global__ __launch_bounds__(128) void k_phi(const float* __restrict__ Lam, const float* __restrict__ We1,
                                             const float* __restrict__ be1, float* __restrict__ phiA) {
    int l = blockIdx.x >> 5, b = blockIdx.x & 31, j = threadIdx.x;
    float acc = be1[l * 128 + j];
    for (int q = 0; q < 8; q++)
        acc = fmaf(Lam[b * 8 + q], We1[l * 1024 + q * 128 + j], acc);
    phiA[l * 4096 + b * 128 + j] = fmaxf(acc, 0.f);
}

// ---- M[l] = Wee[l] @ Wg[l] (16x16 per layer) ----
__global__ __launch_bounds__(256) void k_small(const float* __restrict__ Wee, const float* __restrict__ Wg,
                                               float* __restrict__ MA) {
    int l = blockIdx.x, t = threadIdx.x;
    int k = t >> 4, h = t & 15;
    float m = 0.f;
    for (int f = 0; f < 64; f++)
        m = fmaf(Wee[l * 1024 + k * 64 + f], Wg[l * 1024 + f * 16 + h], m);
    MA[l * 256 + t] = m;
}

// ---- CSR build ----
__global__ __launch_bounds__(256) void k_hist(const int* __restrict__ ei, int* __restrict__ deg) {
    int e = blockIdx.x * 256 + threadIdx.x;
    if (e < EE) {
        int d = ei[EE + e];
        if (d >= 0 && d < NN) atomicAdd(&deg[d], 1);
    }
}

__global__ __launch_bounds__(256) void k_scan1(const int* __restrict__ deg, int* __restrict__ rowptr,
                                               int* __restrict__ bsum) {
    __shared__ int tmp[256];
    int t = threadIdx.x, i = blockIdx.x * 256 + t;
    int v = (i < NN) ? deg[i] : 0;
    tmp[t] = v;
    __syncthreads();
    for (int off = 1; off < 256; off <<= 1) {
        int a = (t >= off) ? tmp[t - off] : 0;
        __syncthreads();
        tmp[t] += a;
        __syncthreads();
    }
    if (i < NN) rowptr[i] = tmp[t] - v;
    if (t == 255) bsum[blockIdx.x] = tmp[255];
}

__global__ __launch_bounds__(256) void k_scan2(const int* __restrict__ bsum, int* __restrict__ boff,
                                               int* __restrict__ rowptr, int nb) {
    __shared__ int tmp[256];
    int t = threadIdx.x;
    int v = (t < nb) ? bsum[t] : 0;
    tmp[t] = v;
    __syncthreads();
    for (int off = 1; off < 256; off <<= 1) {
        int a = (t >= off) ? tmp[t - off] : 0;
        __syncthreads();
        tmp[t] += a;
        __syncthreads();
    }
    if (t < nb) boff[t] = tmp[t] - v;
    if (t == 255) rowptr[NN] = tmp[255];
}

__global__ __launch_bounds__(256) void k_scan3(int* __restrict__ rowptr, const int* __restrict__ boff) {
    int i = blockIdx.x * 256 + threadIdx.x;
    if (i < NN) rowptr[i] += boff[blockIdx.x];
}

__global__ __launch_bounds__(256) void k_scatter(const int* __restrict__ ei, const int* __restrict__ batch,
                                                 const int* __restrict__ rowptr, int* __restrict__ cursor,
                                                 u32* __restrict__ sb, int* __restrict__ eeo) {
    int e = blockIdx.x * 256 + threadIdx.x;
    if (e < EE) {
        int s = ei[e], d = ei[EE + e];
        if (s < 0) s = 0; if (s >= NN) s = NN - 1;
        if (d < 0) d = 0; if (d >= NN) d = NN - 1;
        int pos = rowptr[d] + atomicAdd(&cursor[d], 1);
        if (pos >= 0 && pos < EE) {
            sb[pos] = (u32)s | ((u32)(batch[s] & 31) << 16);
            eeo[pos] = e;
        }
    }
}

// ---- permute edge_attr into CSR order, bf16, float4-wide ----
__global__ __launch_bounds__(256) void k_perm(const float* __restrict__ eat, const int* __restrict__ eeo,
                                              u16* __restrict__ eatp) {
    const float4* e4 = reinterpret_cast<const float4*>(eat);
    ushort4* o4 = reinterpret_cast<ushort4*>(eatp);
    for (long long i = (long long)blockIdx.x * 256 + threadIdx.x; i < (long long)EE * 16;
         i += (long long)gridDim.x * 256) {
        int idx = (int)(i >> 4), cc = (int)(i & 15);
        int e = eeo[idx];
        float4 v = e4[(size_t)e * 16 + cc];
        ushort4 o;
        o.x = f2bf(v.x); o.y = f2bf(v.y); o.z = f2bf(v.z); o.w = f2bf(v.w);
        o4[i] = o;
    }
}

// ---- ALL layers: EAGp4[l][idx][h] = pack( (eatp[idx]+bee[l])@Wg[l] + bg[l] ) ----
__global__ __launch_bounds__(256) void k_eag_all(const u16* __restrict__ eatp, const float* __restrict__ Wg,
                                                 const float* __restrict__ bee, const float* __restrict__ bg,
                                                 u32* __restrict__ EAGp4) {
    __shared__ float sWg[4096];     // 4 layers x 64 x 16
    __shared__ float scv[64];       // 4 layers x 16
    __shared__ u32 srow[256][33];
    const int t = threadIdx.x;
    for (int i = t; i < 4096; i += 256) sWg[i] = Wg[i];
    __syncthreads();
    if (t < 64) {
        const int l = t >> 4, h = t & 15;
        float c = bg[l * 16 + h];
        for (int j = 0; j < 64; j++) c = fmaf(bee[l * 64 + j], sWg[l * 1024 + j * 16 + h], c);
        scv[t] = c;
    }
    const int base = blockIdx.x * 256;
    const u32* eat32 = (const u32*)eatp;
    for (int i = t; i < 256 * 32; i += 256) {
        int r = i >> 5, c = i & 31;
        int idx = base + r;
        srow[r][c] = (idx < EE) ? __builtin_nontemporal_load(&eat32[(size_t)idx * 32 + c]) : 0u;
    }
    __syncthreads();
    const int idx = base + t;
    if (idx >= EE) return;
#pragma unroll
    for (int l = 0; l < LL; l++) {
        const float* wl = &sWg[l * 1024];
        float acc[16];
#pragma unroll
        for (int h = 0; h < 16; h++) acc[h] = scv[l * 16 + h];
#pragma unroll
        for (int c = 0; c < 32; c++) {
            float a0, a1;
            unpack2(srow[t][c], a0, a1);
            const float* w0 = &wl[(2 * c) * 16];
#pragma unroll
            for (int h = 0; h < 16; h++) acc[h] = fmaf(a0, w0[h], fmaf(a1, w0[16 + h], acc[h]));
        }
        u32 w[8];
#pragma unroll
        for (int h = 0; h < 8; h++) w[h] = (u32)f2bf(acc[h]) | ((u32)f2bf(acc[8 + h]) << 16);
        uint4* op = reinterpret_cast<uint4*>(EAGp4 + (size_t)l * EE * 8 + (size_t)idx * 8);
        op[0] = make_uint4(w[0], w[1], w[2], w[3]);
        op[1] = make_uint4(w[4], w[5], w[6], w[7]);
    }
}

// ---- per-layer EAG (big-path fallback when ws can't hold 4 layers) ----
__global__ __launch_bounds__(256) void k_eag2(const u16* __restrict__ eatp, const float* __restrict__ WgL,
                                              const float* __restrict__ beeL, const float* __restrict__ bgL,
                                              u32* __restrict__ EAGp) {
    __shared__ float sWg[1024];
    __shared__ float scv[16];
    __shared__ u32 srow[256][33];
    const int t = threadIdx.x;
    for (int i = t; i < 1024; i += 256) sWg[i] = WgL[i];
    __syncthreads();
    if (t < 16) {
        float c = bgL[t];
        for (int j = 0; j < 64; j++) c = fmaf(beeL[j], sWg[j * 16 + t], c);
        scv[t] = c;
    }
    const int base = blockIdx.x * 256;
    const u32* eat32 = (const u32*)eatp;
    for (int i = t; i < 256 * 32; i += 256) {
        int r = i >> 5, c = i & 31;
        int idx = base + r;
        srow[r][c] = (idx < EE) ? __builtin_nontemporal_load(&eat32[(size_t)idx * 32 + c]) : 0u;
    }
    __syncthreads();
    const int idx = base + t;
    if (idx < EE) {
        float acc[16];
#pragma unroll
        for (int h = 0; h < 16; h++) acc[h] = scv[h];
#pragma unroll
        for (int c = 0; c < 32; c++) {
            float a0, a1;
            unpack2(srow[t][c], a0, a1);
            const float* w0 = &sWg[(2 * c) * 16];
#pragma unroll
            for (int h = 0; h < 16; h++) acc[h] = fmaf(a0, w0[h], fmaf(a1, w0[16 + h], acc[h]));
        }
        u32 w[8];
#pragma unroll
        for (int h = 0; h < 8; h++) w[h] = (u32)f2bf(acc[h]) | ((u32)f2bf(acc[8 + h]) << 16);
        uint4* op = reinterpret_cast<uint4*>(EAGp + (size_t)idx * 8);
        op[0] = make_uint4(w[0], w[1], w[2], w[3]);
        op[1] = make_uint4(w[4], w[5], w[6], w[7]);
    }
}

// ==== BIG-path fused edge pass (round-9 proven structure): chunked sb preload +
//      dual-edge pipeline, gate via redundant parallel mlo/mhi chains.
//      NEW: nontemporal loads for the read-once eatp/EAG streams (preserve L2 for z/x). ====
#define EF(P, kk) do { \
    P##w = (u32)__builtin_amdgcn_readlane((int)svec, (kk)); \
    int s_ = (int)(P##w & 0xffffu); \
    if (INM == 0) { P##z0 = P##z1 = pe[s_ * 8 + pp]; } \
    else { float2 t_ = Z2[s_ * 64 + lane]; P##z0 = t_.x; P##z1 = t_.y; } \
    P##xs = bfc(Xh[s_ * 64 + lane]); \
    size_t ge_ = (size_t)(c + (kk)); \
    P##ea = bfc(__builtin_nontemporal_load(&eatp[ge_ * 64 + lane])); \
    unpack2(__builtin_nontemporal_load(&EAGp[ge_ * 8 + hlo]), P##gl, P##gh); \
} while (0)

#define EC(P, MSK) do { \
    int b_ = (int)((P##w >> 16) & 31u); \
    float p0 = sphi[b_ * 128 + lane] * P##z0 * zd0; \
    float p1 = sphi[b_ * 128 + 64 + lane] * P##z1 * zd1; \
    p0 += __shfl_xor(p0, 1); p1 += __shfl_xor(p1, 1); \
    p0 += __shfl_xor(p0, 2); p1 += __shfl_xor(p1, 2); \
    p0 += __shfl_xor(p0, 4); p1 += __shfl_xor(p1, 4); \
    float eaA = 0.f, eaB = 0.f, gA = P##gl, gB = 0.f, hA = P##gh, hB = 0.f; \
    _Pragma("unroll") \
    for (int k_ = 0; k_ < 8; k_++) { float e_ = lanebc(p0, k_ << 3); \
        eaA = fmaf(e_, wee[k_], eaA); gA = fmaf(e_, mlo[k_], gA); hA = fmaf(e_, mhi[k_], hA); } \
    _Pragma("unroll") \
    for (int k_ = 0; k_ < 8; k_++) { float e_ = lanebc(p1, k_ << 3); \
        eaB = fmaf(e_, wee[8 + k_], eaB); gB = fmaf(e_, mlo[8 + k_], gB); hB = fmaf(e_, mhi[8 + k_], hB); } \
    float ea_ = beev + P##ea + eaA + eaB; \
    accx = fmaf(MSK, fmaxf(0.f, P##xs + ea_), accx); \
    az0  = fmaf(MSK, fmaxf(0.f, P##z0 + fmaxf(gA + gB, 0.f)), az0); \
    az1  = fmaf(MSK, fmaxf(0.f, P##z1 + fmaxf(hA + hB, 0.f)), az1); \
} while (0)

template <int INM, int FIN>
__global__ __launch_bounds__(256) void k_edge2(const float2* __restrict__ Z2,
                                               const float* __restrict__ pe,
                                               const u16* __restrict__ Xh,
                                               const u16* __restrict__ eatp, const u32* __restrict__ EAGp,
                                               const int* __restrict__ rowptr, const u32* __restrict__ sb,
                                               const float* __restrict__ phiL, const float* __restrict__ WeeL,
                                               const float* __restrict__ beeL, const float* __restrict__ ML,
                                               const float* __restrict__ WpL, const float* __restrict__ bpL,
                                               float* __restrict__ Hf, float2* __restrict__ Z2O,
                                               float* __restrict__ outz,
                                               double* __restrict__ stats) {
    __shared__ float sphi[4096];
    __shared__ float sWp[256];
    __shared__ float sbp[16];
    if (blockIdx.x == 0) stats[threadIdx.x] = 0.0;
    for (int t = threadIdx.x; t < 4096; t += 256) sphi[t] = phiL[t];
    if (threadIdx.x < 256) sWp[threadIdx.x] = WpL[threadIdx.x];
    if (threadIdx.x < 16) sbp[threadIdx.x] = bpL[threadIdx.x];
    const int lane = threadIdx.x & 63;
    const int wid = threadIdx.x >> 6;
    const int hlo = lane >> 3;
    const int pp = lane & 7;
    float wee[16], mlo[16], mhi[16];
#pragma unroll
    for (int k = 0; k < 16; k++) {
        wee[k] = WeeL[k * 64 + lane];
        mlo[k] = ML[k * 16 + hlo];
        mhi[k] = ML[k * 16 + 8 + hlo];
    }
    const float beev = beeL[lane];
    __syncthreads();
    for (int n = blockIdx.x * 4 + wid; n < NN; n += gridDim.x * 4) {
        float zd0, zd1;
        if (INM == 0) { zd0 = zd1 = pe[n * 8 + pp]; }
        else { float2 t = Z2[n * 64 + lane]; zd0 = t.x; zd1 = t.y; }
        float accx = bfc(Xh[n * 64 + lane]);
        float az0 = zd0, az1 = zd1;
        int i0 = rowptr[n], i1 = rowptr[n + 1];
        if (i0 < 0) i0 = 0;
        if (i1 > EE) i1 = EE;
        for (int c = i0; c < i1; c += 64) {
            const int ce = (c + 64 < i1) ? c + 64 : i1;
            const int m = ce - c;         // 1..64 edges this chunk
            const int mL = m - 1;
            int ci = c + lane; if (ci > i1 - 1) ci = i1 - 1;
            const u32 svec = sb[ci];      // whole chunk's (src|batch) in one load
            u32 Aw, Bw, Nw, Mw;
            float Az0, Az1, Axs, Aea, Agl, Agh;
            float Bz0, Bz1, Bxs, Bea, Bgl, Bgh;
            float Nz0, Nz1, Nxs, Nea, Ngl, Ngh;
            float Mz0, Mz1, Mxs, Mea, Mgl, Mgh;
            EF(A, 0);
            EF(B, (1 > mL ? mL : 1));
            for (int k = 0; k < m; k += 2) {
                const int n0 = (k + 2 > mL) ? mL : k + 2;
                const int n1 = (k + 3 > mL) ? mL : k + 3;
                EF(N, n0);
                EF(M, n1);
                EC(A, 1.f);
                EC(B, (k + 1 <= mL) ? 1.f : 0.f);
                Aw = Nw; Az0 = Nz0; Az1 = Nz1; Axs = Nxs; Aea = Nea; Agl = Ngl; Agh = Ngh;
                Bw = Mw; Bz0 = Mz0; Bz1 = Mz1; Bxs = Mxs; Bea = Mea; Bgl = Mgl; Bgh = Mgh;
            }
        }
        Hf[n * 64 + lane] = accx;
        float r0 = sbp[hlo], r1 = sbp[8 + hlo];
#pragma unroll
        for (int h = 0; h < 8; h++) {
            const float v = __shfl(az0, (h << 3) + pp);
            r0 = fmaf(v, sWp[h * 16 + hlo], r0);
            r1 = fmaf(v, sWp[h * 16 + 8 + hlo], r1);
        }
#pragma unroll
        for (int h = 0; h < 8; h++) {
            const float v = __shfl(az1, (h << 3) + pp);
            r0 = fmaf(v, sWp[(8 + h) * 16 + hlo], r0);
            r1 = fmaf(v, sWp[(8 + h) * 16 + 8 + hlo], r1);
        }
        if (FIN) {
            outz[n * 128 + lane] = r0;
            outz[n * 128 + 64 + lane] = r1;
        } else {
            Z2O[n * 64 + lane] = make_float2(r0, r1);
        }
    }
}

// ==== SMALL-path fused edge pass (round-4, proven fallback) ====
template <int INM>
__global__ __launch_bounds__(256) void k_edge_s(const float* __restrict__ Zf,
                                                const float* __restrict__ pe,
                                                const float* __restrict__ Xf, const float* __restrict__ eat,
                                                const int* __restrict__ rowptr, const u32* __restrict__ sb,
                                                const int* __restrict__ eeo,
                                                const float* __restrict__ phiL, const float* __restrict__ WeeL,
                                                const float* __restrict__ beeL,
                                                const float* __restrict__ WgL, const float* __restrict__ bgL,
                                                const float* __restrict__ WpL, const float* __restrict__ bpL,
                                                float* __restrict__ Hf, float* __restrict__ ZfO,
                                                double* __restrict__ stats) {
    __shared__ float sphi[32 * 128];
    __shared__ float sWp[256];
    __shared__ float sbp[16];
    if (blockIdx.x == 0) stats[threadIdx.x] = 0.0;
    for (int t = threadIdx.x; t < 4096; t += 256) sphi[t] = phiL[t];
    if (threadIdx.x < 256) sWp[threadIdx.x] = WpL[threadIdx.x];
    if (threadIdx.x < 16) sbp[threadIdx.x] = bpL[threadIdx.x];
    const int lane = threadIdx.x & 63;
    const int wid = threadIdx.x >> 6;
    const int hlo = lane >> 3;
    const int pp = lane & 7;
    const int h16 = lane & 15;
    const int g16 = lane & 48;
    float wee[16], wgr[16];
#pragma unroll
    for (int k = 0; k < 16; k++) {
        wee[k] = WeeL[k * 64 + lane];
        wgr[k] = WgL[(g16 + k) * 16 + h16];
    }
    const float beev = beeL[lane];
    const float bgr = bgL[h16];
    __syncthreads();
    for (int n = blockIdx.x * 4 + wid; n < NN; n += gridDim.x * 4) {
        float zd0, zd1;
        if (INM == 0) { zd0 = zd1 = pe[n * 8 + pp]; }
        else { zd0 = Zf[n * 128 + lane]; zd1 = Zf[n * 128 + 64 + lane]; }
        float accx = Xf[n * 64 + lane];
        float az0 = zd0, az1 = zd1;
        int i0 = rowptr[n], i1 = rowptr[n + 1];
        if (i0 < 0) i0 = 0;
        if (i1 > EE) i1 = EE;
        for (int idx = i0; idx < i1; ++idx) {
            const u32 w = sb[idx];
            const int s = w & 0xffff;
            const int b = (w >> 16) & 31;
            int e = eeo[idx];
            e = (e < 0) ? 0 : ((e >= EE) ? EE - 1 : e);
            float zs0, zs1;
            if (INM == 0) { zs0 = zs1 = pe[s * 8 + pp]; }
            else { zs0 = Zf[s * 128 + lane]; zs1 = Zf[s * 128 + 64 + lane]; }
            float p0 = sphi[b * 128 + lane] * zs0 * zd0;
            float p1 = sphi[b * 128 + 64 + lane] * zs1 * zd1;
            p0 += __shfl_xor(p0, 1); p1 += __shfl_xor(p1, 1);
            p0 += __shfl_xor(p0, 2); p1 += __shfl_xor(p1, 2);
            p0 += __shfl_xor(p0, 4); p1 += __shfl_xor(p1, 4);
            float ea = beev + eat[(size_t)e * 64 + lane];
#pragma unroll
            for (int k = 0; k < 8; k++) ea = fmaf(lanebc(p0, k << 3), wee[k], ea);
#pragma unroll
            for (int k = 0; k < 8; k++) ea = fmaf(lanebc(p1, k << 3), wee[8 + k], ea);
            float gp = 0.f;
#pragma unroll
            for (int i = 0; i < 16; i++) gp = fmaf(__shfl(ea, g16 + i), wgr[i], gp);
            gp += __shfl_xor(gp, 16);
            gp += __shfl_xor(gp, 32);
            const float gv = fmaxf(gp + bgr, 0.f);
            const float glo = __shfl(gv, hlo);
            const float ghi = __shfl(gv, 8 + hlo);
            const float xs = Xf[s * 64 + lane];
            accx += fmaxf(0.f, xs + ea);
            az0 += fmaxf(0.f, zs0 + glo);
            az1 += fmaxf(0.f, zs1 + ghi);
        }
        Hf[n * 64 + lane] = accx;
        float r0 = sbp[hlo], r1 = sbp[8 + hlo];
#pragma unroll
        for (int h = 0; h < 8; h++) {
            const float v = __shfl(az0, (h << 3) + pp);
            r0 = fmaf(v, sWp[h * 16 + hlo], r0);
            r1 = fmaf(v, sWp[h * 16 + 8 + hlo], r1);
        }
#pragma unroll
        for (int h = 0; h < 8; h++) {
            const float v = __shfl(az1, (h << 3) + pp);
            r0 = fmaf(v, sWp[(8 + h) * 16 + hlo], r0);
            r1 = fmaf(v, sWp[(8 + h) * 16 + 8 + hlo], r1);
        }
        ZfO[n * 128 + lane] = r0;
        ZfO[n * 128 + 64 + lane] = r1;
    }
}

// ---- t = h @ W1 + b1 (in-place on Hf), fused BN1 stats ----
__global__ __launch_bounds__(256) void k_gemm1(float* Buf, const float* __restrict__ WL,
                                               const float* __restrict__ bL,
                                               double* __restrict__ sum, double* __restrict__ sq) {
    __shared__ float sW[4096];
    __shared__ double red[512];
    for (int t = threadIdx.x; t < 4096; t += 256) sW[t] = WL[t];
    const int lane = threadIdx.x & 63, wid = threadIdx.x >> 6;
    const float bv = bL[lane];
    __syncthreads();
    double s = 0.0, q = 0.0;
    for (int n = blockIdx.x * 4 + wid; n < NN; n += gridDim.x * 4) {
        const float h = Buf[n * 64 + lane];
        float a0 = bv, a1 = 0.f;
#pragma unroll
        for (int k = 0; k < 32; k++) a0 = fmaf(lanebc(h, k), sW[k * 64 + lane], a0);
#pragma unroll
        for (int k = 32; k < 64; k++) a1 = fmaf(lanebc(h, k), sW[k * 64 + lane], a1);
        const float acc = a0 + a1;
        Buf[n * 64 + lane] = acc;
        s += (double)acc;
        q += (double)acc * (double)acc;
    }
    red[threadIdx.x] = s;
    red[256 + threadIdx.x] = q;
    __syncthreads();
    if (threadIdx.x < 64) {
        s = red[threadIdx.x] + red[threadIdx.x + 64] + red[threadIdx.x + 128] + red[threadIdx.x + 192];
        q = red[256 + threadIdx.x] + red[320 + threadIdx.x] + red[384 + threadIdx.x] + red[448 + threadIdx.x];
        atomicAdd(&sum[lane], s);
        atomicAdd(&sq[lane], q);
    }
}

// ---- h2 = relu(BN1(t)) @ W2 + b2 (in-place on Hf), fused BN2 stats ----
__global__ __launch_bounds__(256) void k_gemm2(float* Buf, const float* __restrict__ WL,
                                               const float* __restrict__ bL,
                                               const float* __restrict__ gL, const float* __restrict__ betaL,
                                               const double* __restrict__ s1, const double* __restrict__ q1,
                                               double* __restrict__ sum, double* __restrict__ sq) {
    __shared__ float sW[4096];
    __shared__ double red[512];
    for (int t = threadIdx.x; t < 4096; t += 256) sW[t] = WL[t];
    const int lane = threadIdx.x & 63, wid = threadIdx.x >> 6;
    const float bv = bL[lane];
    const double mu = s1[lane] * (1.0 / NN);
    const double var = q1[lane] * (1.0 / NN) - mu * mu;
    const float inv = rsqrtf(fmaxf((float)var, 0.f) + 1e-5f);
    const float gm = gL[lane] * inv;
    const float ga = betaL[lane] - (float)mu * gm;
    __syncthreads();
    double s = 0.0, q = 0.0;
    for (int n = blockIdx.x * 4 + wid; n < NN; n += gridDim.x * 4) {
        const float v = Buf[n * 64 + lane];
        const float r = fmaxf(fmaf(v, gm, ga), 0.f);
        float a0 = bv, a1 = 0.f;
#pragma unroll
        for (int k = 0; k < 32; k++) a0 = fmaf(lanebc(r, k), sW[k * 64 + lane], a0);
#pragma unroll
        for (int k = 32; k < 64; k++) a1 = fmaf(lanebc(r, k), sW[k * 64 + lane], a1);
        const float acc = a0 + a1;
        Buf[n * 64 + lane] = acc;
        s += (double)acc;
        q += (double)acc * (double)acc;
    }
    red[threadIdx.x] = s;
    red[256 + threadIdx.x] = q;
    __syncthreads();
    if (threadIdx.x < 64) {
        s = red[threadIdx.x] + red[threadIdx.x + 64] + red[threadIdx.x + 128] + red[threadIdx.x + 192];
        q = red[256 + threadIdx.x] + red[320 + threadIdx.x] + red[384 + threadIdx.x] + red[448 + threadIdx.x];
        atomicAdd(&sum[lane], s);
        atomicAdd(&sq[lane], q);
    }
}

// ---- big path: x = BN2(h2); layers 0-2 -> bf16 Xh with relu; layer 3 -> fp32 out ----
__global__ __launch_bounds__(256) void k_bnout2(const float* __restrict__ In, u16* __restrict__ Xh,
                                                float* __restrict__ outx,
                                                const double* __restrict__ s2, const double* __restrict__ q2,
                                                const float* __restrict__ gL, const float* __restrict__ bL,
                                                int last) {
    int i = blockIdx.x * 256 + threadIdx.x;
    const int f = i & 63;
    const double mu = s2[f] * (1.0 / NN);
    const double var = q2[f] * (1.0 / NN) - mu * mu;
    const float inv = rsqrtf(fmaxf((float)var, 0.f) + 1e-5f);
    const float gm = gL[f] * inv;
    const float ga = bL[f] - (float)mu * gm;
    for (; i < NN * 64; i += gridDim.x * 256) {
        float o = fmaf(In[i], gm, ga);
        if (last) {
            outx[i] = o;
        } else {
            o = fmaxf(o, 0.f);
            Xh[i] = f2bf(o);
        }
    }
}

// ---- small path bnout (fp32 x state) ----
__global__ __launch_bounds__(256) void k_bnout(const float* __restrict__ In, float* __restrict__ Xf,
                                               const double* __restrict__ s2, const double* __restrict__ q2,
                                               const float* __restrict__ gL, const float* __restrict__ bL,
                                               int dorelu) {
    int i = blockIdx.x * 256 + threadIdx.x;
    const int f = i & 63;
    const double mu = s2[f] * (1.0 / NN);
    const double var = q2[f] * (1.0 / NN) - mu * mu;
    const float inv = rsqrtf(fmaxf((float)var, 0.f) + 1e-5f);
    const float gm = gL[f] * inv;
    const float ga = bL[f] - (float)mu * gm;
    for (; i < NN * 64; i += gridDim.x * 256) {
        float o = fmaf(In[i], gm, ga);
        if (dorelu) o = fmaxf(o, 0.f);
        Xf[i] = o;
    }
}

extern "C" void kernel_launch(void* const* d_in, const int* in_sizes, int n_in,
                              void* d_out, int out_size, void* d_ws, size_t ws_size,
                              hipStream_t stream) {
    (void)in_sizes; (void)n_in; (void)out_size;
    const float* x    = (const float*)d_in[0];
    const float* pe   = (const float*)d_in[1];
    const float* Lam  = (const float*)d_in[2];
    const float* eat  = (const float*)d_in[3];
    const int*   ei   = (const int*)d_in[4];
    const int*   batch= (const int*)d_in[5];
    const float* We1  = (const float*)d_in[6];
    const float* be1  = (const float*)d_in[7];
    const float* Wee  = (const float*)d_in[8];
    const float* bee  = (const float*)d_in[9];
    const float* W1   = (const float*)d_in[10];
    const float* b1   = (const float*)d_in[11];
    const float* g1   = (const float*)d_in[12];
    const float* bt1  = (const float*)d_in[13];
    const float* W2   = (const float*)d_in[14];
    const float* b2   = (const float*)d_in[15];
    const float* Wg   = (const float*)d_in[16];
    const float* bg   = (const float*)d_in[17];
    const float* Wp   = (const float*)d_in[18];
    const float* bp   = (const float*)d_in[19];
    const float* gn   = (const float*)d_in[20];
    const float* bnb  = (const float*)d_in[21];

    // output regions
    float* Xf   = (float*)d_out;              // [N,64]
    u16*   Xh   = (u16*)d_out;                // big path: bf16 x state in out-x region
    float* B    = (float*)d_out + 3200000;    // [N,128] z region

    // workspace layout
    float* A    = (float*)d_ws;                 // z plane [N][128] fp32, 25.6 MB
    float* Hf   = A + 6400000;
    float* MA   = Hf + 3200000;
    float* phiA = MA + 1024;
    double* stats = (double*)(phiA + 16384);
    double* s1 = stats, *q1 = stats + 64, *s2 = stats + 128, *q2 = stats + 192;
    int* rowptr = (int*)(stats + 256);
    int* deg    = rowptr + NN + 1;
    int* bsum   = deg + NN;
    int* boff   = bsum + 256;
    int* cursor = boff + 256;
    u32* sb     = (u32*)(cursor + NN);          // EE
    int* eeo    = (int*)(sb + EE);              // EE
    u16* eatp   = (u16*)(eeo + EE);             // EE*64 u16 (64 MB)
    u32* EAGp   = (u32*)(eatp + (size_t)EE * 64); // EE*8 u32 per layer
    const size_t NEED_BIG  = (size_t)((char*)(EAGp + (size_t)EE * 8) - (char*)d_ws);
    const size_t NEED_BIG2 = (size_t)((char*)(EAGp + (size_t)EE * 32) - (char*)d_ws);
    const bool big2 = (ws_size >= NEED_BIG2);
    const bool big  = (ws_size >= NEED_BIG);

    float2* A2 = (float2*)A;
    float2* B2 = (float2*)B;

    const int NB_N = (NN + 255) / 256;
    const int NB_E = (EE + 255) / 256;

    k_init<<<1024, 256, 0, stream>>>(x, Xf, Xh, big ? 1 : 0, deg, cursor);
    k_phi<<<LL * 32, 128, 0, stream>>>(Lam, We1, be1, phiA);
    k_hist<<<NB_E, 256, 0, stream>>>(ei, deg);
    k_scan1<<<NB_N, 256, 0, stream>>>(deg, rowptr, bsum);
    k_scan2<<<1, 256, 0, stream>>>(bsum, boff, rowptr, NB_N);
    k_scan3<<<NB_N, 256, 0, stream>>>(rowptr, boff);
    k_scatter<<<NB_E, 256, 0, stream>>>(ei, batch, rowptr, cursor, sb, eeo);
    if (big) {
        k_small<<<LL, 256, 0, stream>>>(Wee, Wg, MA);
        k_perm<<<4096, 256, 0, stream>>>(eat, eeo, eatp);
        if (big2)
            k_eag_all<<<NB_E, 256, 0, stream>>>(eatp, Wg, bee, bg, EAGp);
    }

    for (int l = 0; l < LL; l++) {
        const float* WeeL = Wee + l * 1024;
        const float* beeL = bee + l * 64;
        const float* WgL  = Wg + l * 1024;
        const float* bgL  = bg + l * 16;
        const float* WpL  = Wp + l * 256;
        const float* bpL  = bp + l * 16;
        const float* phiL = phiA + l * 4096;
        const float* ML   = MA + l * 256;
        if (big) {
            const u32* EAGl = big2 ? (EAGp + (size_t)l * EE * 8) : EAGp;
            if (!big2)
                k_eag2<<<NB_E, 256, 0, stream>>>(eatp, WgL, beeL, bgL, EAGp);
            // z schedule: l0 pe->A2, l1 A2->B2, l2 B2->A2, l3 A2->B(final std layout)
            if (l == 0)
                k_edge2<0, 0><<<6272, 256, 0, stream>>>(A2, pe, Xh, eatp, EAGl, rowptr, sb,
                                                        phiL, WeeL, beeL, ML, WpL, bpL,
                                                        Hf, A2, nullptr, stats);
            else if (l == 1)
                k_edge2<1, 0><<<6272, 256, 0, stream>>>(A2, pe, Xh, eatp, EAGl, rowptr, sb,
                                                        phiL, WeeL, beeL, ML, WpL, bpL,
                                                        Hf, B2, nullptr, stats);
            else if (l == 2)
                k_edge2<1, 0><<<6272, 256, 0, stream>>>(B2, pe, Xh, eatp, EAGl, rowptr, sb,
                                                        phiL, WeeL, beeL, ML, WpL, bpL,
                                                        Hf, A2, nullptr, stats);
            else
                k_edge2<1, 1><<<6272, 256, 0, stream>>>(A2, pe, Xh, eatp, EAGl, rowptr, sb,
                                                        phiL, WeeL, beeL, ML, WpL, bpL,
                                                        Hf, nullptr, B, stats);
        } else {
            const float* Zin  = (l == 2) ? B : A;
            float*       Zout = (l == 1 || l == 3) ? B : A;
            if (l == 0)
                k_edge_s<0><<<2048, 256, 0, stream>>>(nullptr, pe, Xf, eat, rowptr, sb, eeo,
                                                      phiL, WeeL, beeL, WgL, bgL, WpL, bpL,
                                                      Hf, Zout, stats);
            else
                k_edge_s<1><<<2048, 256, 0, stream>>>(Zin, pe, Xf, eat, rowptr, sb, eeo,
                                                      phiL, WeeL, beeL, WgL, bgL, WpL, bpL,
                                                      Hf, Zout, stats);
        }
        k_gemm1<<<512, 256, 0, stream>>>(Hf, W1 + l * 4096, b1 + l * 64, s1, q1);
        k_gemm2<<<512, 256, 0, stream>>>(Hf, W2 + l * 4096, b2 + l * 64,
                                         g1 + l * 64, bt1 + l * 64, s1, q1, s2, q2);
        if (big)
            k_bnout2<<<1024, 256, 0, stream>>>(Hf, Xh, Xf, s2, q2, gn + l * 64, bnb + l * 64,
                                               (l == LL - 1) ? 1 : 0);
        else
            k_bnout<<<1024, 256, 0, stream>>>(Hf, Xf, s2, q2, gn + l * 64, bnb + l * 64,
                                              (l == LL - 1) ? 0 : 1);
    }
}

// Round 12
// 1061.132 us; speedup vs baseline: 1.1820x; 1.0830x over previous
//
#include <hip/hip_runtime.h>

#define NN 50000
#define EE 500000
#define LL 4

typedef unsigned short u16;
typedef unsigned int u32;

__device__ __forceinline__ float bfc(u16 u) { return __uint_as_float(((u32)u) << 16); }
__device__ __forceinline__ u16 f2bf(float f) {
    u32 u = __float_as_uint(f);
    return (u16)((u + 0x7fffu + ((u >> 16) & 1u)) >> 16);
}
__device__ __forceinline__ float lanebc(float v, int l) {
    return __int_as_float(__builtin_amdgcn_readlane(__float_as_int(v), l));
}
__device__ __forceinline__ void unpack2(u32 w, float& lo, float& hi) {
    lo = __uint_as_float(w << 16);
    hi = __uint_as_float(w & 0xffff0000u);
}
// fp16 helpers: z planes stored as 2xfp16 pre-scaled by 1/16
__device__ __forceinline__ float h2f(u16 u) {
    _Float16 h;
    __builtin_memcpy(&h, &u, 2);
    return (float)h;
}
__device__ __forceinline__ u16 f2h(float f) {
    _Float16 h = (_Float16)f;
    u16 u;
    __builtin_memcpy(&u, &h, 2);
    return u;
}
__device__ __forceinline__ void unpackz(u32 w, float& z0, float& z1) {
    z0 = h2f((u16)(w & 0xffffu)) * 16.f;
    z1 = h2f((u16)(w >> 16)) * 16.f;
}
__device__ __forceinline__ u32 packz(float r0, float r1) {
    return (u32)f2h(r0 * 0.0625f) | ((u32)f2h(r1 * 0.0625f) << 16);
}

// ---- init: x state (bf16 Xh if big, fp32 Xf if small); zero deg/cursor ----
__global__ __launch_bounds__(256) void k_init(const float* __restrict__ x, float* __restrict__ Xf,
                                              u16* __restrict__ Xh, int big,
                                              int* __restrict__ deg, int* __restrict__ cursor) {
    for (int i = blockIdx.x * 256 + threadIdx.x; i < NN * 64; i += gridDim.x * 256) {
        if (big) Xh[i] = f2bf(x[i]);
        else Xf[i] = x[i];
    }
    for (int i = blockIdx.x * 256 + threadIdx.x; i < NN; i += gridDim.x * 256) {
        deg[i] = 0;
        cursor[i] = 0;
    }
}

// ---- phi[l,b,:] = relu(Lambda[b] @ We1[l] + be1[l]) ----
__global__ __launch_bounds__(128) void k_phi(const float* __restrict__ Lam, const float* __restrict__ We1,
                                             const float* __restrict__ be1, float* __restrict__ phiA) {
    int l = blockIdx.x >> 5, b = blockIdx.x & 31, j = threadIdx.x;
    float acc = be1[l * 128 + j];
    for (int q = 0; q < 8; q++)
        acc = fmaf(Lam[b * 8 + q], We1[l * 1024 + q * 128 + j], acc);
    phiA[l * 4096 + b * 128 + j] = fmaxf(acc, 0.f);
}

// ---- M[l] = Wee[l] @ Wg[l] (16x16 per layer) ----
__global__ __launch_bounds__(256) void k_small(const float* __restrict__ Wee, const float* __restrict__ Wg,
                                               float* __restrict__ MA) {
    int l = blockIdx.x, t = threadIdx.x;
    int k = t >> 4, h = t & 15;
    float m = 0.f;
    for (int f = 0; f < 64; f++)
        m = fmaf(Wee[l * 1024 + k * 64 + f], Wg[l * 1024 + f * 16 + h], m);
    MA[l * 256 + t] = m;
}

// ---- CSR build ----
__global__ __launch_bounds__(256) void k_hist(const int* __restrict__ ei, int* __restrict__ deg) {
    int e = blockIdx.x * 256 + threadIdx.x;
    if (e < EE) {
        int d = ei[EE + e];
        if (d >= 0 && d < NN) atomicAdd(&deg[d], 1);
    }
}

__global__ __launch_bounds__(256) void k_scan1(const int* __restrict__ deg, int* __restrict__ rowptr,
                                               int* __restrict__ bsum) {
    __shared__ int tmp[256];
    int t = threadIdx.x, i = blockIdx.x * 256 + t;
    int v = (i < NN) ? deg[i] : 0;
    tmp[t] = v;
    __syncthreads();
    for (int off = 1; off < 256; off <<= 1) {
        int a = (t >= off) ? tmp[t - off] : 0;
        __syncthreads();
        tmp[t] += a;
        __syncthreads();
    }
    if (i < NN) rowptr[i] = tmp[t] - v;
    if (t == 255) bsum[blockIdx.x] = tmp[255];
}

__global__ __launch_bounds__(256) void k_scan2(const int* __restrict__ bsum, int* __restrict__ boff,
                                               int* __restrict__ rowptr, int nb) {
    __shared__ int tmp[256];
    int t = threadIdx.x;
    int v = (t < nb) ? bsum[t] : 0;
    tmp[t] = v;
    __syncthreads();
    for (int off = 1; off < 256; off <<= 1) {
        int a = (t >= off) ? tmp[t - off] : 0;
        __syncthreads();
        tmp[t] += a;
        __syncthreads();
    }
    if (t < nb) boff[t] = tmp[t] - v;
    if (t == 255) rowptr[NN] = tmp[255];
}

__global__ __launch_bounds__(256) void k_scan3(int* __restrict__ rowptr, const int* __restrict__ boff) {
    int i = blockIdx.x * 256 + threadIdx.x;
    if (i < NN) rowptr[i] += boff[blockIdx.x];
}

__global__ __launch_bounds__(256) void k_scatter(const int* __restrict__ ei, const int* __restrict__ batch,
                                                 const int* __restrict__ rowptr, int* __restrict__ cursor,
                                                 u32* __restrict__ sb, int* __restrict__ eeo) {
    int e = blockIdx.x * 256 + threadIdx.x;
    if (e < EE) {
        int s = ei[e], d = ei[EE + e];
        if (s < 0) s = 0; if (s >= NN) s = NN - 1;
        if (d < 0) d = 0; if (d >= NN) d = NN - 1;
        int pos = rowptr[d] + atomicAdd(&cursor[d], 1);
        if (pos >= 0 && pos < EE) {
            sb[pos] = (u32)s | ((u32)(batch[s] & 31) << 16);
            eeo[pos] = e;
        }
    }
}

// ---- permute edge_attr into CSR order, bf16, float4-wide ----
__global__ __launch_bounds__(256) void k_perm(const float* __restrict__ eat, const int* __restrict__ eeo,
                                              u16* __restrict__ eatp) {
    const float4* e4 = reinterpret_cast<const float4*>(eat);
    ushort4* o4 = reinterpret_cast<ushort4*>(eatp);
    for (long long i = (long long)blockIdx.x * 256 + threadIdx.x; i < (long long)EE * 16;
         i += (long long)gridDim.x * 256) {
        int idx = (int)(i >> 4), cc = (int)(i & 15);
        int e = eeo[idx];
        float4 v = e4[(size_t)e * 16 + cc];
        ushort4 o;
        o.x = f2bf(v.x); o.y = f2bf(v.y); o.z = f2bf(v.z); o.w = f2bf(v.w);
        o4[i] = o;
    }
}

// ---- ALL layers: EAGp4[l][idx][h] = pack( (eatp[idx]+bee[l])@Wg[l] + bg[l] ) ----
__global__ __launch_bounds__(256) void k_eag_all(const u16* __restrict__ eatp, const float* __restrict__ Wg,
                                                 const float* __restrict__ bee, const float* __restrict__ bg,
                                                 u32* __restrict__ EAGp4) {
    __shared__ float sWg[4096];     // 4 layers x 64 x 16
    __shared__ float scv[64];       // 4 layers x 16
    __shared__ u32 srow[256][33];
    const int t = threadIdx.x;
    for (int i = t; i < 4096; i += 256) sWg[i] = Wg[i];
    __syncthreads();
    if (t < 64) {
        const int l = t >> 4, h = t & 15;
        float c = bg[l * 16 + h];
        for (int j = 0; j < 64; j++) c = fmaf(bee[l * 64 + j], sWg[l * 1024 + j * 16 + h], c);
        scv[t] = c;
    }
    const int base = blockIdx.x * 256;
    const u32* eat32 = (const u32*)eatp;
    for (int i = t; i < 256 * 32; i += 256) {
        int r = i >> 5, c = i & 31;
        int idx = base + r;
        srow[r][c] = (idx < EE) ? eat32[(size_t)idx * 32 + c] : 0u;
    }
    __syncthreads();
    const int idx = base + t;
    if (idx >= EE) return;
#pragma unroll
    for (int l = 0; l < LL; l++) {
        const float* wl = &sWg[l * 1024];
        float acc[16];
#pragma unroll
        for (int h = 0; h < 16; h++) acc[h] = scv[l * 16 + h];
#pragma unroll
        for (int c = 0; c < 32; c++) {
            float a0, a1;
            unpack2(srow[t][c], a0, a1);
            const float* w0 = &wl[(2 * c) * 16];
#pragma unroll
            for (int h = 0; h < 16; h++) acc[h] = fmaf(a0, w0[h], fmaf(a1, w0[16 + h], acc[h]));
        }
        u32 w[8];
#pragma unroll
        for (int h = 0; h < 8; h++) w[h] = (u32)f2bf(acc[h]) | ((u32)f2bf(acc[8 + h]) << 16);
        uint4* op = reinterpret_cast<uint4*>(EAGp4 + (size_t)l * EE * 8 + (size_t)idx * 8);
        op[0] = make_uint4(w[0], w[1], w[2], w[3]);
        op[1] = make_uint4(w[4], w[5], w[6], w[7]);
    }
}

// ---- per-layer EAG (big-path fallback when ws can't hold 4 layers) ----
__global__ __launch_bounds__(256) void k_eag2(const u16* __restrict__ eatp, const float* __restrict__ WgL,
                                              const float* __restrict__ beeL, const float* __restrict__ bgL,
                                              u32* __restrict__ EAGp) {
    __shared__ float sWg[1024];
    __shared__ float scv[16];
    __shared__ u32 srow[256][33];
    const int t = threadIdx.x;
    for (int i = t; i < 1024; i += 256) sWg[i] = WgL[i];
    __syncthreads();
    if (t < 16) {
        float c = bgL[t];
        for (int j = 0; j < 64; j++) c = fmaf(beeL[j], sWg[j * 16 + t], c);
        scv[t] = c;
    }
    const int base = blockIdx.x * 256;
    const u32* eat32 = (const u32*)eatp;
    for (int i = t; i < 256 * 32; i += 256) {
        int r = i >> 5, c = i & 31;
        int idx = base + r;
        srow[r][c] = (idx < EE) ? eat32[(size_t)idx * 32 + c] : 0u;
    }
    __syncthreads();
    const int idx = base + t;
    if (idx < EE) {
        float acc[16];
#pragma unroll
        for (int h = 0; h < 16; h++) acc[h] = scv[h];
#pragma unroll
        for (int c = 0; c < 32; c++) {
            float a0, a1;
            unpack2(srow[t][c], a0, a1);
            const float* w0 = &sWg[(2 * c) * 16];
#pragma unroll
            for (int h = 0; h < 16; h++) acc[h] = fmaf(a0, w0[h], fmaf(a1, w0[16 + h], acc[h]));
        }
        u32 w[8];
#pragma unroll
        for (int h = 0; h < 8; h++) w[h] = (u32)f2bf(acc[h]) | ((u32)f2bf(acc[8 + h]) << 16);
        uint4* op = reinterpret_cast<uint4*>(EAGp + (size_t)idx * 8);
        op[0] = make_uint4(w[0], w[1], w[2], w[3]);
        op[1] = make_uint4(w[4], w[5], w[6], w[7]);
    }
}

// ==== BIG-path fused edge pass (round-9 structure; z planes = packed fp16/16x) ====
// INM: 0 = z from pe (layer 0), 1 = packed fp16 plane Zu
// FIN: 0 = write packed fp16 plane, 1 = write final standard [n][128] fp32
#define EF(P, kk) do { \
    P##w = (u32)__builtin_amdgcn_readlane((int)svec, (kk)); \
    int s_ = (int)(P##w & 0xffffu); \
    if (INM == 0) { P##z0 = P##z1 = pe[s_ * 8 + pp]; } \
    else { unpackz(Zu[s_ * 64 + lane], P##z0, P##z1); } \
    P##xs = bfc(Xh[s_ * 64 + lane]); \
    size_t ge_ = (size_t)(c + (kk)); \
    P##ea = bfc(eatp[ge_ * 64 + lane]); \
    unpack2(EAGp[ge_ * 8 + hlo], P##gl, P##gh); \
} while (0)

#define EC(P, MSK) do { \
    int b_ = (int)((P##w >> 16) & 31u); \
    float p0 = sphi[b_ * 128 + lane] * P##z0 * zd0; \
    float p1 = sphi[b_ * 128 + 64 + lane] * P##z1 * zd1; \
    p0 += __shfl_xor(p0, 1); p1 += __shfl_xor(p1, 1); \
    p0 += __shfl_xor(p0, 2); p1 += __shfl_xor(p1, 2); \
    p0 += __shfl_xor(p0, 4); p1 += __shfl_xor(p1, 4); \
    float eaA = 0.f, eaB = 0.f, gA = P##gl, gB = 0.f, hA = P##gh, hB = 0.f; \
    _Pragma("unroll") \
    for (int k_ = 0; k_ < 8; k_++) { float e_ = lanebc(p0, k_ << 3); \
        eaA = fmaf(e_, wee[k_], eaA); gA = fmaf(e_, mlo[k_], gA); hA = fmaf(e_, mhi[k_], hA); } \
    _Pragma("unroll") \
    for (int k_ = 0; k_ < 8; k_++) { float e_ = lanebc(p1, k_ << 3); \
        eaB = fmaf(e_, wee[8 + k_], eaB); gB = fmaf(e_, mlo[8 + k_], gB); hB = fmaf(e_, mhi[8 + k_], hB); } \
    float ea_ = beev + P##ea + eaA + eaB; \
    accx = fmaf(MSK, fmaxf(0.f, P##xs + ea_), accx); \
    az0  = fmaf(MSK, fmaxf(0.f, P##z0 + fmaxf(gA + gB, 0.f)), az0); \
    az1  = fmaf(MSK, fmaxf(0.f, P##z1 + fmaxf(hA + hB, 0.f)), az1); \
} while (0)

template <int INM, int FIN>
__global__ __launch_bounds__(256) void k_edge2(const u32* __restrict__ Zu,
                                               const float* __restrict__ pe,
                                               const u16* __restrict__ Xh,
                                               const u16* __restrict__ eatp, const u32* __restrict__ EAGp,
                                               const int* __restrict__ rowptr, const u32* __restrict__ sb,
                                               const float* __restrict__ phiL, const float* __restrict__ WeeL,
                                               const float* __restrict__ beeL, const float* __restrict__ ML,
                                               const float* __restrict__ WpL, const float* __restrict__ bpL,
                                               float* __restrict__ Hf, u32* __restrict__ ZuO,
                                               float* __restrict__ outz,
                                               double* __restrict__ stats) {
    __shared__ float sphi[4096];
    __shared__ float sWp[256];
    __shared__ float sbp[16];
    if (blockIdx.x == 0) stats[threadIdx.x] = 0.0;
    for (int t = threadIdx.x; t < 4096; t += 256) sphi[t] = phiL[t];
    if (threadIdx.x < 256) sWp[threadIdx.x] = WpL[threadIdx.x];
    if (threadIdx.x < 16) sbp[threadIdx.x] = bpL[threadIdx.x];
    const int lane = threadIdx.x & 63;
    const int wid = threadIdx.x >> 6;
    const int hlo = lane >> 3;
    const int pp = lane & 7;
    float wee[16], mlo[16], mhi[16];
#pragma unroll
    for (int k = 0; k < 16; k++) {
        wee[k] = WeeL[k * 64 + lane];
        mlo[k] = ML[k * 16 + hlo];
        mhi[k] = ML[k * 16 + 8 + hlo];
    }
    const float beev = beeL[lane];
    __syncthreads();
    for (int n = blockIdx.x * 4 + wid; n < NN; n += gridDim.x * 4) {
        float zd0, zd1;
        if (INM == 0) { zd0 = zd1 = pe[n * 8 + pp]; }
        else { unpackz(Zu[n * 64 + lane], zd0, zd1); }
        float accx = bfc(Xh[n * 64 + lane]);
        float az0 = zd0, az1 = zd1;
        int i0 = rowptr[n], i1 = rowptr[n + 1];
        if (i0 < 0) i0 = 0;
        if (i1 > EE) i1 = EE;
        for (int c = i0; c < i1; c += 64) {
            const int ce = (c + 64 < i1) ? c + 64 : i1;
            const int m = ce - c;         // 1..64 edges this chunk
            const int mL = m - 1;
            int ci = c + lane; if (ci > i1 - 1) ci = i1 - 1;
            const u32 svec = sb[ci];      // whole chunk's (src|batch) in one load
            u32 Aw, Bw, Nw, Mw;
            float Az0, Az1, Axs, Aea, Agl, Agh;
            float Bz0, Bz1, Bxs, Bea, Bgl, Bgh;
            float Nz0, Nz1, Nxs, Nea, Ngl, Ngh;
            float Mz0, Mz1, Mxs, Mea, Mgl, Mgh;
            EF(A, 0);
            EF(B, (1 > mL ? mL : 1));
            for (int k = 0; k < m; k += 2) {
                const int n0 = (k + 2 > mL) ? mL : k + 2;
                const int n1 = (k + 3 > mL) ? mL : k + 3;
                EF(N, n0);
                EF(M, n1);
                EC(A, 1.f);
                EC(B, (k + 1 <= mL) ? 1.f : 0.f);
                Aw = Nw; Az0 = Nz0; Az1 = Nz1; Axs = Nxs; Aea = Nea; Agl = Ngl; Agh = Ngh;
                Bw = Mw; Bz0 = Mz0; Bz1 = Mz1; Bxs = Mxs; Bea = Mea; Bgl = Mgl; Bgh = Mgh;
            }
        }
        Hf[n * 64 + lane] = accx;
        float r0 = sbp[hlo], r1 = sbp[8 + hlo];
#pragma unroll
        for (int h = 0; h < 8; h++) {
            const float v = __shfl(az0, (h << 3) + pp);
            r0 = fmaf(v, sWp[h * 16 + hlo], r0);
            r1 = fmaf(v, sWp[h * 16 + 8 + hlo], r1);
        }
#pragma unroll
        for (int h = 0; h < 8; h++) {
            const float v = __shfl(az1, (h << 3) + pp);
            r0 = fmaf(v, sWp[(8 + h) * 16 + hlo], r0);
            r1 = fmaf(v, sWp[(8 + h) * 16 + 8 + hlo], r1);
        }
        if (FIN) {
            outz[n * 128 + lane] = r0;
            outz[n * 128 + 64 + lane] = r1;
        } else {
            ZuO[n * 64 + lane] = packz(r0, r1);
        }
    }
}

// ==== SMALL-path fused edge pass (round-4, proven fallback) ====
template <int INM>
__global__ __launch_bounds__(256) void k_edge_s(const float* __restrict__ Zf,
                                                const float* __restrict__ pe,
                                                const float* __restrict__ Xf, const float* __restrict__ eat,
                                                const int* __restrict__ rowptr, const u32* __restrict__ sb,
                                                const int* __restrict__ eeo,
                                                const float* __restrict__ phiL, const float* __restrict__ WeeL,
                                                const float* __restrict__ beeL,
                                                const float* __restrict__ WgL, const float* __restrict__ bgL,
                                                const float* __restrict__ WpL, const float* __restrict__ bpL,
                                                float* __restrict__ Hf, float* __restrict__ ZfO,
                                                double* __restrict__ stats) {
    __shared__ float sphi[32 * 128];
    __shared__ float sWp[256];
    __shared__ float sbp[16];
    if (blockIdx.x == 0) stats[threadIdx.x] = 0.0;
    for (int t = threadIdx.x; t < 4096; t += 256) sphi[t] = phiL[t];
    if (threadIdx.x < 256) sWp[threadIdx.x] = WpL[threadIdx.x];
    if (threadIdx.x < 16) sbp[threadIdx.x] = bpL[threadIdx.x];
    const int lane = threadIdx.x & 63;
    const int wid = threadIdx.x >> 6;
    const int hlo = lane >> 3;
    const int pp = lane & 7;
    const int h16 = lane & 15;
    const int g16 = lane & 48;
    float wee[16], wgr[16];
#pragma unroll
    for (int k = 0; k < 16; k++) {
        wee[k] = WeeL[k * 64 + lane];
        wgr[k] = WgL[(g16 + k) * 16 + h16];
    }
    const float beev = beeL[lane];
    const float bgr = bgL[h16];
    __syncthreads();
    for (int n = blockIdx.x * 4 + wid; n < NN; n += gridDim.x * 4) {
        float zd0, zd1;
        if (INM == 0) { zd0 = zd1 = pe[n * 8 + pp]; }
        else { zd0 = Zf[n * 128 + lane]; zd1 = Zf[n * 128 + 64 + lane]; }
        float accx = Xf[n * 64 + lane];
        float az0 = zd0, az1 = zd1;
        int i0 = rowptr[n], i1 = rowptr[n + 1];
        if (i0 < 0) i0 = 0;
        if (i1 > EE) i1 = EE;
        for (int idx = i0; idx < i1; ++idx) {
            const u32 w = sb[idx];
            const int s = w & 0xffff;
            const int b = (w >> 16) & 31;
            int e = eeo[idx];
            e = (e < 0) ? 0 : ((e >= EE) ? EE - 1 : e);
            float zs0, zs1;
            if (INM == 0) { zs0 = zs1 = pe[s * 8 + pp]; }
            else { zs0 = Zf[s * 128 + lane]; zs1 = Zf[s * 128 + 64 + lane]; }
            float p0 = sphi[b * 128 + lane] * zs0 * zd0;
            float p1 = sphi[b * 128 + 64 + lane] * zs1 * zd1;
            p0 += __shfl_xor(p0, 1); p1 += __shfl_xor(p1, 1);
            p0 += __shfl_xor(p0, 2); p1 += __shfl_xor(p1, 2);
            p0 += __shfl_xor(p0, 4); p1 += __shfl_xor(p1, 4);
            float ea = beev + eat[(size_t)e * 64 + lane];
#pragma unroll
            for (int k = 0; k < 8; k++) ea = fmaf(lanebc(p0, k << 3), wee[k], ea);
#pragma unroll
            for (int k = 0; k < 8; k++) ea = fmaf(lanebc(p1, k << 3), wee[8 + k], ea);
            float gp = 0.f;
#pragma unroll
            for (int i = 0; i < 16; i++) gp = fmaf(__shfl(ea, g16 + i), wgr[i], gp);
            gp += __shfl_xor(gp, 16);
            gp += __shfl_xor(gp, 32);
            const float gv = fmaxf(gp + bgr, 0.f);
            const float glo = __shfl(gv, hlo);
            const float ghi = __shfl(gv, 8 + hlo);
            const float xs = Xf[s * 64 + lane];
            accx += fmaxf(0.f, xs + ea);
            az0 += fmaxf(0.f, zs0 + glo);
            az1 += fmaxf(0.f, zs1 + ghi);
        }
        Hf[n * 64 + lane] = accx;
        float r0 = sbp[hlo], r1 = sbp[8 + hlo];
#pragma unroll
        for (int h = 0; h < 8; h++) {
            const float v = __shfl(az0, (h << 3) + pp);
            r0 = fmaf(v, sWp[h * 16 + hlo], r0);
            r1 = fmaf(v, sWp[h * 16 + 8 + hlo], r1);
        }
#pragma unroll
        for (int h = 0; h < 8; h++) {
            const float v = __shfl(az1, (h << 3) + pp);
            r0 = fmaf(v, sWp[(8 + h) * 16 + hlo], r0);
            r1 = fmaf(v, sWp[(8 + h) * 16 + 8 + hlo], r1);
        }
        ZfO[n * 128 + lane] = r0;
        ZfO[n * 128 + 64 + lane] = r1;
    }
}

// ---- t = h @ W1 + b1 (in-place on Hf), fused BN1 stats ----
__global__ __launch_bounds__(256) void k_gemm1(float* Buf, const float* __restrict__ WL,
                                               const float* __restrict__ bL,
                                               double* __restrict__ sum, double* __restrict__ sq) {
    __shared__ float sW[4096];
    __shared__ double red[512];
    for (int t = threadIdx.x; t < 4096; t += 256) sW[t] = WL[t];
    const int lane = threadIdx.x & 63, wid = threadIdx.x >> 6;
    const float bv = bL[lane];
    __syncthreads();
    double s = 0.0, q = 0.0;
    for (int n = blockIdx.x * 4 + wid; n < NN; n += gridDim.x * 4) {
        const float h = Buf[n * 64 + lane];
        float a0 = bv, a1 = 0.f;
#pragma unroll
        for (int k = 0; k < 32; k++) a0 = fmaf(lanebc(h, k), sW[k * 64 + lane], a0);
#pragma unroll
        for (int k = 32; k < 64; k++) a1 = fmaf(lanebc(h, k), sW[k * 64 + lane], a1);
        const float acc = a0 + a1;
        Buf[n * 64 + lane] = acc;
        s += (double)acc;
        q += (double)acc * (double)acc;
    }
    red[threadIdx.x] = s;
    red[256 + threadIdx.x] = q;
    __syncthreads();
    if (threadIdx.x < 64) {
        s = red[threadIdx.x] + red[threadIdx.x + 64] + red[threadIdx.x + 128] + red[threadIdx.x + 192];
        q = red[256 + threadIdx.x] + red[320 + threadIdx.x] + red[384 + threadIdx.x] + red[448 + threadIdx.x];
        atomicAdd(&sum[lane], s);
        atomicAdd(&sq[lane], q);
    }
}

// ---- h2 = relu(BN1(t)) @ W2 + b2 (in-place on Hf), fused BN2 stats ----
__global__ __launch_bounds__(256) void k_gemm2(float* Buf, const float* __restrict__ WL,
                                               const float* __restrict__ bL,
                                               const float* __restrict__ gL, const float* __restrict__ betaL,
                                               const double* __restrict__ s1, const double* __restrict__ q1,
                                               double* __restrict__ sum, double* __restrict__ sq) {
    __shared__ float sW[4096];
    __shared__ double red[512];
    for (int t = threadIdx.x; t < 4096; t += 256) sW[t] = WL[t];
    const int lane = threadIdx.x & 63, wid = threadIdx.x >> 6;
    const float bv = bL[lane];
    const double mu = s1[lane] * (1.0 / NN);
    const double var = q1[lane] * (1.0 / NN) - mu * mu;
    const float inv = rsqrtf(fmaxf((float)var, 0.f) + 1e-5f);
    const float gm = gL[lane] * inv;
    const float ga = betaL[lane] - (float)mu * gm;
    __syncthreads();
    double s = 0.0, q = 0.0;
    for (int n = blockIdx.x * 4 + wid; n < NN; n += gridDim.x * 4) {
        const float v = Buf[n * 64 + lane];
        const float r = fmaxf(fmaf(v, gm, ga), 0.f);
        float a0 = bv, a1 = 0.f;
#pragma unroll
        for (int k = 0; k < 32; k++) a0 = fmaf(lanebc(r, k), sW[k * 64 + lane], a0);
#pragma unroll
        for (int k = 32; k < 64; k++) a1 = fmaf(lanebc(r, k), sW[k * 64 + lane], a1);
        const float acc = a0 + a1;
        Buf[n * 64 + lane] = acc;
        s += (double)acc;
        q += (double)acc * (double)acc;
    }
    red[threadIdx.x] = s;
    red[256 + threadIdx.x] = q;
    __syncthreads();
    if (threadIdx.x < 64) {
        s = red[threadIdx.x] + red[threadIdx.x + 64] + red[threadIdx.x + 128] + red[threadIdx.x + 192];
        q = red[256 + threadIdx.x] + red[320 + threadIdx.x] + red[384 + threadIdx.x] + red[448 + threadIdx.x];
        atomicAdd(&sum[lane], s);
        atomicAdd(&sq[lane], q);
    }
}

// ---- big path: x = BN2(h2); layers 0-2 -> bf16 Xh with relu; layer 3 -> fp32 out ----
__global__ __launch_bounds__(256) void k_bnout2(const float* __restrict__ In, u16* __restrict__ Xh,
                                                float* __restrict__ outx,
                                                const double* __restrict__ s2, const double* __restrict__ q2,
                                                const float* __restrict__ gL, const float* __restrict__ bL,
                                                int last) {
    int i = blockIdx.x * 256 + threadIdx.x;
    const int f = i & 63;
    const double mu = s2[f] * (1.0 / NN);
    const double var = q2[f] * (1.0 / NN) - mu * mu;
    const float inv = rsqrtf(fmaxf((float)var, 0.f) + 1e-5f);
    const float gm = gL[f] * inv;
    const float ga = bL[f] - (float)mu * gm;
    for (; i < NN * 64; i += gridDim.x * 256) {
        float o = fmaf(In[i], gm, ga);
        if (last) {
            outx[i] = o;
        } else {
            o = fmaxf(o, 0.f);
            Xh[i] = f2bf(o);
        }
    }
}

// ---- small path bnout (fp32 x state) ----
__global__ __launch_bounds__(256) void k_bnout(const float* __restrict__ In, float* __restrict__ Xf,
                                               const double* __restrict__ s2, const double* __restrict__ q2,
                                               const float* __restrict__ gL, const float* __restrict__ bL,
                                               int dorelu) {
    int i = blockIdx.x * 256 + threadIdx.x;
    const int f = i & 63;
    const double mu = s2[f] * (1.0 / NN);
    const double var = q2[f] * (1.0 / NN) - mu * mu;
    const float inv = rsqrtf(fmaxf((float)var, 0.f) + 1e-5f);
    const float gm = gL[f] * inv;
    const float ga = bL[f] - (float)mu * gm;
    for (; i < NN * 64; i += gridDim.x * 256) {
        float o = fmaf(In[i], gm, ga);
        if (dorelu) o = fmaxf(o, 0.f);
        Xf[i] = o;
    }
}

extern "C" void kernel_launch(void* const* d_in, const int* in_sizes, int n_in,
                              void* d_out, int out_size, void* d_ws, size_t ws_size,
                              hipStream_t stream) {
    (void)in_sizes; (void)n_in; (void)out_size;
    const float* x    = (const float*)d_in[0];
    const float* pe   = (const float*)d_in[1];
    const float* Lam  = (const float*)d_in[2];
    const float* eat  = (const float*)d_in[3];
    const int*   ei   = (const int*)d_in[4];
    const int*   batch= (const int*)d_in[5];
    const float* We1  = (const float*)d_in[6];
    const float* be1  = (const float*)d_in[7];
    const float* Wee  = (const float*)d_in[8];
    const float* bee  = (const float*)d_in[9];
    const float* W1   = (const float*)d_in[10];
    const float* b1   = (const float*)d_in[11];
    const float* g1   = (const float*)d_in[12];
    const float* bt1  = (const float*)d_in[13];
    const float* W2   = (const float*)d_in[14];
    const float* b2   = (const float*)d_in[15];
    const float* Wg   = (const float*)d_in[16];
    const float* bg   = (const float*)d_in[17];
    const float* Wp   = (const float*)d_in[18];
    const float* bp   = (const float*)d_in[19];
    const float* gn   = (const float*)d_in[20];
    const float* bnb  = (const float*)d_in[21];

    // output regions
    float* Xf   = (float*)d_out;              // [N,64]
    u16*   Xh   = (u16*)d_out;                // big path: bf16 x state in out-x region
    float* B    = (float*)d_out + 3200000;    // [N,128] z region (final fp32 z / small-path plane)

    // workspace layout
    u32* Az     = (u32*)d_ws;                   // packed fp16 z plane [N*64], 12.8 MB
    u32* Bz     = Az + 3200000;                 // second packed plane, 12.8 MB
    float* Afp  = (float*)d_ws;                 // small path: fp32 z plane [N*128] (overlays Az+Bz)
    float* Hf   = (float*)(Bz + 3200000);       // [N,64] fp32
    float* MA   = Hf + 3200000;
    float* phiA = MA + 1024;
    double* stats = (double*)(phiA + 16384);
    double* s1 = stats, *q1 = stats + 64, *s2 = stats + 128, *q2 = stats + 192;
    int* rowptr = (int*)(stats + 256);
    int* deg    = rowptr + NN + 1;
    int* bsum   = deg + NN;
    int* boff   = bsum + 256;
    int* cursor = boff + 256;
    u32* sb     = (u32*)(cursor + NN);          // EE
    int* eeo    = (int*)(sb + EE);              // EE
    u16* eatp   = (u16*)(eeo + EE);             // EE*64 u16 (64 MB)
    u32* EAGp   = (u32*)(eatp + (size_t)EE * 64); // EE*8 u32 per layer
    const size_t NEED_BIG  = (size_t)((char*)(EAGp + (size_t)EE * 8) - (char*)d_ws);
    const size_t NEED_BIG2 = (size_t)((char*)(EAGp + (size_t)EE * 32) - (char*)d_ws);
    const bool big2 = (ws_size >= NEED_BIG2);
    const bool big  = (ws_size >= NEED_BIG);

    const int NB_N = (NN + 255) / 256;
    const int NB_E = (EE + 255) / 256;

    k_init<<<1024, 256, 0, stream>>>(x, Xf, Xh, big ? 1 : 0, deg, cursor);
    k_phi<<<LL * 32, 128, 0, stream>>>(Lam, We1, be1, phiA);
    k_hist<<<NB_E, 256, 0, stream>>>(ei, deg);
    k_scan1<<<NB_N, 256, 0, stream>>>(deg, rowptr, bsum);
    k_scan2<<<1, 256, 0, stream>>>(bsum, boff, rowptr, NB_N);
    k_scan3<<<NB_N, 256, 0, stream>>>(rowptr, boff);
    k_scatter<<<NB_E, 256, 0, stream>>>(ei, batch, rowptr, cursor, sb, eeo);
    if (big) {
        k_small<<<LL, 256, 0, stream>>>(Wee, Wg, MA);
        k_perm<<<4096, 256, 0, stream>>>(eat, eeo, eatp);
        if (big2)
            k_eag_all<<<NB_E, 256, 0, stream>>>(eatp, Wg, bee, bg, EAGp);
    }

    for (int l = 0; l < LL; l++) {
        const float* WeeL = Wee + l * 1024;
        const float* beeL = bee + l * 64;
        const float* WgL  = Wg + l * 1024;
        const float* bgL  = bg + l * 16;
        const float* WpL  = Wp + l * 256;
        const float* bpL  = bp + l * 16;
        const float* phiL = phiA + l * 4096;
        const float* ML   = MA + l * 256;
        if (big) {
            const u32* EAGl = big2 ? (EAGp + (size_t)l * EE * 8) : EAGp;
            if (!big2)
                k_eag2<<<NB_E, 256, 0, stream>>>(eatp, WgL, beeL, bgL, EAGp);
            // z schedule: l0 pe->Az, l1 Az->Bz, l2 Bz->Az, l3 Az->B(final fp32)
            if (l == 0)
                k_edge2<0, 0><<<6272, 256, 0, stream>>>(Az, pe, Xh, eatp, EAGl, rowptr, sb,
                                                        phiL, WeeL, beeL, ML, WpL, bpL,
                                                        Hf, Az, nullptr, stats);
            else if (l == 1)
                k_edge2<1, 0><<<6272, 256, 0, stream>>>(Az, pe, Xh, eatp, EAGl, rowptr, sb,
                                                        phiL, WeeL, beeL, ML, WpL, bpL,
                                                        Hf, Bz, nullptr, stats);
            else if (l == 2)
                k_edge2<1, 0><<<6272, 256, 0, stream>>>(Bz, pe, Xh, eatp, EAGl, rowptr, sb,
                                                        phiL, WeeL, beeL, ML, WpL, bpL,
                                                        Hf, Az, nullptr, stats);
            else
                k_edge2<1, 1><<<6272, 256, 0, stream>>>(Az, pe, Xh, eatp, EAGl, rowptr, sb,
                                                        phiL, WeeL, beeL, ML, WpL, bpL,
                                                        Hf, nullptr, B, stats);
        } else {
            const float* Zin  = (l == 2) ? B : Afp;
            float*       Zout = (l == 1 || l == 3) ? B : Afp;
            if (l == 0)
                k_edge_s<0><<<2048, 256, 0, stream>>>(nullptr, pe, Xf, eat, rowptr, sb, eeo,
                                                      phiL, WeeL, beeL, WgL, bgL, WpL, bpL,
                                                      Hf, Zout, stats);
            else
                k_edge_s<1><<<2048, 256, 0, stream>>>(Zin, pe, Xf, eat, rowptr, sb, eeo,
                                                      phiL, WeeL, beeL, WgL, bgL, WpL, bpL,
                                                      Hf, Zout, stats);
        }
        k_gemm1<<<512, 256, 0, stream>>>(Hf, W1 + l * 4096, b1 + l * 64, s1, q1);
        k_gemm2<<<512, 256, 0, stream>>>(Hf, W2 + l * 4096, b2 + l * 64,
                                         g1 + l * 64, bt1 + l * 64, s1, q1, s2, q2);
        if (big)
            k_bnout2<<<1024, 256, 0, stream>>>(Hf, Xh, Xf, s2, q2, gn + l * 64, bnb + l * 64,
                                               (l == LL - 1) ? 1 : 0);
        else
            k_bnout<<<1024, 256, 0, stream>>>(Hf, Xf, s2, q2, gn + l * 64, bnb + l * 64,
                                              (l == LL - 1) ? 0 : 1);
    }
}

// Round 13
// 1002.768 us; speedup vs baseline: 1.2508x; 1.0582x over previous
//
#include <hip/hip_runtime.h>

#define NN 50000
#define EE 500000
#define LL 4

typedef unsigned short u16;
typedef unsigned int u32;

__device__ __forceinline__ float bfc(u16 u) { return __uint_as_float(((u32)u) << 16); }
__device__ __forceinline__ u16 f2bf(float f) {
    u32 u = __float_as_uint(f);
    return (u16)((u + 0x7fffu + ((u >> 16) & 1u)) >> 16);
}
__device__ __forceinline__ float lanebc(float v, int l) {
    return __int_as_float(__builtin_amdgcn_readlane(__float_as_int(v), l));
}
__device__ __forceinline__ void unpack2(u32 w, float& lo, float& hi) {
    lo = __uint_as_float(w << 16);
    hi = __uint_as_float(w & 0xffff0000u);
}

// ---- init: x state (bf16 Xh if big, fp32 Xf if small); zero deg/cursor/stats ----
__global__ __launch_bounds__(256) void k_init(const float* __restrict__ x, float* __restrict__ Xf,
                                              u16* __restrict__ Xh, int big,
                                              int* __restrict__ deg, int* __restrict__ cursor,
                                              double* __restrict__ statsAll) {
    for (int i = blockIdx.x * 256 + threadIdx.x; i < NN * 64; i += gridDim.x * 256) {
        if (big) Xh[i] = f2bf(x[i]);
        else Xf[i] = x[i];
    }
    for (int i = blockIdx.x * 256 + threadIdx.x; i < NN; i += gridDim.x * 256) {
        deg[i] = 0;
        cursor[i] = 0;
    }
    for (int i = blockIdx.x * 256 + threadIdx.x; i < LL * 256; i += gridDim.x * 256)
        statsAll[i] = 0.0;
}

// ---- phi[l,b,:] = relu(Lambda[b] @ We1[l] + be1[l]) ----
__global__ __launch_bounds__(128) void k_phi(const float* __restrict__ Lam, const float* __restrict__ We1,
                                             const float* __restrict__ be1, float* __restrict__ phiA) {
    int l = blockIdx.x >> 5, b = blockIdx.x & 31, j = threadIdx.x;
    float acc = be1[l * 128 + j];
    for (int q = 0; q < 8; q++)
        acc = fmaf(Lam[b * 8 + q], We1[l * 1024 + q * 128 + j], acc);
    phiA[l * 4096 + b * 128 + j] = fmaxf(acc, 0.f);
}

// ---- M[l] = Wee[l] @ Wg[l] (16x16 per layer) ----
__global__ __launch_bounds__(256) void k_small(const float* __restrict__ Wee, const float* __restrict__ Wg,
                                               float* __restrict__ MA) {
    int l = blockIdx.x, t = threadIdx.x;
    int k = t >> 4, h = t & 15;
    float m = 0.f;
    for (int f = 0; f < 64; f++)
        m = fmaf(Wee[l * 1024 + k * 64 + f], Wg[l * 1024 + f * 16 + h], m);
    MA[l * 256 + t] = m;
}

// ---- CSR build ----
__global__ __launch_bounds__(256) void k_hist(const int* __restrict__ ei, int* __restrict__ deg) {
    int e = blockIdx.x * 256 + threadIdx.x;
    if (e < EE) {
        int d = ei[EE + e];
        if (d >= 0 && d < NN) atomicAdd(&deg[d], 1);
    }
}

__global__ __launch_bounds__(256) void k_scan1(const int* __restrict__ deg, int* __restrict__ rowptr,
                                               int* __restrict__ bsum) {
    __shared__ int tmp[256];
    int t = threadIdx.x, i = blockIdx.x * 256 + t;
    int v = (i < NN) ? deg[i] : 0;
    tmp[t] = v;
    __syncthreads();
    for (int off = 1; off < 256; off <<= 1) {
        int a = (t >= off) ? tmp[t - off] : 0;
        __syncthreads();
        tmp[t] += a;
        __syncthreads();
    }
    if (i < NN) rowptr[i] = tmp[t] - v;
    if (t == 255) bsum[blockIdx.x] = tmp[255];
}

__global__ __launch_bounds__(256) void k_scan2(const int* __restrict__ bsum, int* __restrict__ boff,
                                               int* __restrict__ rowptr, int nb) {
    __shared__ int tmp[256];
    int t = threadIdx.x;
    int v = (t < nb) ? bsum[t] : 0;
    tmp[t] = v;
    __syncthreads();
    for (int off = 1; off < 256; off <<= 1) {
        int a = (t >= off) ? tmp[t - off] : 0;
        __syncthreads();
        tmp[t] += a;
        __syncthreads();
    }
    if (t < nb) boff[t] = tmp[t] - v;
    if (t == 255) rowptr[NN] = tmp[255];
}

__global__ __launch_bounds__(256) void k_scan3(int* __restrict__ rowptr, const int* __restrict__ boff) {
    int i = blockIdx.x * 256 + threadIdx.x;
    if (i < NN) rowptr[i] += boff[blockIdx.x];
}

__global__ __launch_bounds__(256) void k_scatter(const int* __restrict__ ei, const int* __restrict__ batch,
                                                 const int* __restrict__ rowptr, int* __restrict__ cursor,
                                                 u32* __restrict__ sb, int* __restrict__ eeo) {
    int e = blockIdx.x * 256 + threadIdx.x;
    if (e < EE) {
        int s = ei[e], d = ei[EE + e];
        if (s < 0) s = 0; if (s >= NN) s = NN - 1;
        if (d < 0) d = 0; if (d >= NN) d = NN - 1;
        int pos = rowptr[d] + atomicAdd(&cursor[d], 1);
        if (pos >= 0 && pos < EE) {
            sb[pos] = (u32)s | ((u32)(batch[s] & 31) << 16);
            eeo[pos] = e;
        }
    }
}

// ---- permute edge_attr into CSR order, bf16, float4-wide ----
__global__ __launch_bounds__(256) void k_perm(const float* __restrict__ eat, const int* __restrict__ eeo,
                                              u16* __restrict__ eatp) {
    const float4* e4 = reinterpret_cast<const float4*>(eat);
    ushort4* o4 = reinterpret_cast<ushort4*>(eatp);
    for (long long i = (long long)blockIdx.x * 256 + threadIdx.x; i < (long long)EE * 16;
         i += (long long)gridDim.x * 256) {
        int idx = (int)(i >> 4), cc = (int)(i & 15);
        int e = eeo[idx];
        float4 v = e4[(size_t)e * 16 + cc];
        ushort4 o;
        o.x = f2bf(v.x); o.y = f2bf(v.y); o.z = f2bf(v.z); o.w = f2bf(v.w);
        o4[i] = o;
    }
}

// ---- ALL layers: EAGp4[l][idx][h] = pack( (eatp[idx]+bee[l])@Wg[l] + bg[l] ) ----
__global__ __launch_bounds__(256) void k_eag_all(const u16* __restrict__ eatp, const float* __restrict__ Wg,
                                                 const float* __restrict__ bee, const float* __restrict__ bg,
                                                 u32* __restrict__ EAGp4) {
    __shared__ float sWg[4096];
    __shared__ float scv[64];
    __shared__ u32 srow[256][33];
    const int t = threadIdx.x;
    for (int i = t; i < 4096; i += 256) sWg[i] = Wg[i];
    __syncthreads();
    if (t < 64) {
        const int l = t >> 4, h = t & 15;
        float c = bg[l * 16 + h];
        for (int j = 0; j < 64; j++) c = fmaf(bee[l * 64 + j], sWg[l * 1024 + j * 16 + h], c);
        scv[t] = c;
    }
    const int base = blockIdx.x * 256;
    const u32* eat32 = (const u32*)eatp;
    for (int i = t; i < 256 * 32; i += 256) {
        int r = i >> 5, c = i & 31;
        int idx = base + r;
        srow[r][c] = (idx < EE) ? eat32[(size_t)idx * 32 + c] : 0u;
    }
    __syncthreads();
    const int idx = base + t;
    if (idx >= EE) return;
#pragma unroll
    for (int l = 0; l < LL; l++) {
        const float* wl = &sWg[l * 1024];
        float acc[16];
#pragma unroll
        for (int h = 0; h < 16; h++) acc[h] = scv[l * 16 + h];
#pragma unroll
        for (int c = 0; c < 32; c++) {
            float a0, a1;
            unpack2(srow[t][c], a0, a1);
            const float* w0 = &wl[(2 * c) * 16];
#pragma unroll
            for (int h = 0; h < 16; h++) acc[h] = fmaf(a0, w0[h], fmaf(a1, w0[16 + h], acc[h]));
        }
        u32 w[8];
#pragma unroll
        for (int h = 0; h < 8; h++) w[h] = (u32)f2bf(acc[h]) | ((u32)f2bf(acc[8 + h]) << 16);
        uint4* op = reinterpret_cast<uint4*>(EAGp4 + (size_t)l * EE * 8 + (size_t)idx * 8);
        op[0] = make_uint4(w[0], w[1], w[2], w[3]);
        op[1] = make_uint4(w[4], w[5], w[6], w[7]);
    }
}

// ---- per-layer EAG (big-path fallback) ----
__global__ __launch_bounds__(256) void k_eag2(const u16* __restrict__ eatp, const float* __restrict__ WgL,
                                              const float* __restrict__ beeL, const float* __restrict__ bgL,
                                              u32* __restrict__ EAGp) {
    __shared__ float sWg[1024];
    __shared__ float scv[16];
    __shared__ u32 srow[256][33];
    const int t = threadIdx.x;
    for (int i = t; i < 1024; i += 256) sWg[i] = WgL[i];
    __syncthreads();
    if (t < 16) {
        float c = bgL[t];
        for (int j = 0; j < 64; j++) c = fmaf(beeL[j], sWg[j * 16 + t], c);
        scv[t] = c;
    }
    const int base = blockIdx.x * 256;
    const u32* eat32 = (const u32*)eatp;
    for (int i = t; i < 256 * 32; i += 256) {
        int r = i >> 5, c = i & 31;
        int idx = base + r;
        srow[r][c] = (idx < EE) ? eat32[(size_t)idx * 32 + c] : 0u;
    }
    __syncthreads();
    const int idx = base + t;
    if (idx < EE) {
        float acc[16];
#pragma unroll
        for (int h = 0; h < 16; h++) acc[h] = scv[h];
#pragma unroll
        for (int c = 0; c < 32; c++) {
            float a0, a1;
            unpack2(srow[t][c], a0, a1);
            const float* w0 = &sWg[(2 * c) * 16];
#pragma unroll
            for (int h = 0; h < 16; h++) acc[h] = fmaf(a0, w0[h], fmaf(a1, w0[16 + h], acc[h]));
        }
        u32 w[8];
#pragma unroll
        for (int h = 0; h < 8; h++) w[h] = (u32)f2bf(acc[h]) | ((u32)f2bf(acc[8 + h]) << 16);
        uint4* op = reinterpret_cast<uint4*>(EAGp + (size_t)idx * 8);
        op[0] = make_uint4(w[0], w[1], w[2], w[3]);
        op[1] = make_uint4(w[4], w[5], w[6], w[7]);
    }
}

// ==== BIG-path fused edge pass (round-9 proven structure) + on-the-fly BN on x ====
// INM: 0 = z from pe (layer 0), 1 = float2 plane
// FIN: 0 = write float2 plane, 1 = write final [n][128] fp32
// XBN: 0 = x state is direct bf16; 1 = x = relu(BN(raw bf16 h2)) applied on the fly
#define EF(P, kk) do { \
    P##w = (u32)__builtin_amdgcn_readlane((int)svec, (kk)); \
    int s_ = (int)(P##w & 0xffffu); \
    if (INM == 0) { P##z0 = P##z1 = pe[s_ * 8 + pp]; } \
    else { float2 t_ = Z2[s_ * 64 + lane]; P##z0 = t_.x; P##z1 = t_.y; } \
    P##xs = XBN ? fmaxf(0.f, fmaf(bfc(Xh[s_ * 64 + lane]), gmx, gax)) \
                : bfc(Xh[s_ * 64 + lane]); \
    size_t ge_ = (size_t)(c + (kk)); \
    P##ea = bfc(eatp[ge_ * 64 + lane]); \
    unpack2(EAGp[ge_ * 8 + hlo], P##gl, P##gh); \
} while (0)

#define EC(P, MSK) do { \
    int b_ = (int)((P##w >> 16) & 31u); \
    float p0 = sphi[b_ * 128 + lane] * P##z0 * zd0; \
    float p1 = sphi[b_ * 128 + 64 + lane] * P##z1 * zd1; \
    p0 += __shfl_xor(p0, 1); p1 += __shfl_xor(p1, 1); \
    p0 += __shfl_xor(p0, 2); p1 += __shfl_xor(p1, 2); \
    p0 += __shfl_xor(p0, 4); p1 += __shfl_xor(p1, 4); \
    float eaA = 0.f, eaB = 0.f, gA = P##gl, gB = 0.f, hA = P##gh, hB = 0.f; \
    _Pragma("unroll") \
    for (int k_ = 0; k_ < 8; k_++) { float e_ = lanebc(p0, k_ << 3); \
        eaA = fmaf(e_, wee[k_], eaA); gA = fmaf(e_, mlo[k_], gA); hA = fmaf(e_, mhi[k_], hA); } \
    _Pragma("unroll") \
    for (int k_ = 0; k_ < 8; k_++) { float e_ = lanebc(p1, k_ << 3); \
        eaB = fmaf(e_, wee[8 + k_], eaB); gB = fmaf(e_, mlo[8 + k_], gB); hB = fmaf(e_, mhi[8 + k_], hB); } \
    float ea_ = beev + P##ea + eaA + eaB; \
    accx = fmaf(MSK, fmaxf(0.f, P##xs + ea_), accx); \
    az0  = fmaf(MSK, fmaxf(0.f, P##z0 + fmaxf(gA + gB, 0.f)), az0); \
    az1  = fmaf(MSK, fmaxf(0.f, P##z1 + fmaxf(hA + hB, 0.f)), az1); \
} while (0)

template <int INM, int FIN, int XBN>
__global__ __launch_bounds__(256) void k_edge2(const float2* __restrict__ Z2,
                                               const float* __restrict__ pe,
                                               const u16* __restrict__ Xh,
                                               const u16* __restrict__ eatp, const u32* __restrict__ EAGp,
                                               const int* __restrict__ rowptr, const u32* __restrict__ sb,
                                               const float* __restrict__ phiL, const float* __restrict__ WeeL,
                                               const float* __restrict__ beeL, const float* __restrict__ ML,
                                               const float* __restrict__ WpL, const float* __restrict__ bpL,
                                               float* __restrict__ Hf, float2* __restrict__ Z2O,
                                               float* __restrict__ outz,
                                               const float* __restrict__ gnP, const float* __restrict__ bnbP,
                                               const double* __restrict__ s2P, const double* __restrict__ q2P) {
    __shared__ float sphi[4096];
    __shared__ float sWp[256];
    __shared__ float sbp[16];
    for (int t = threadIdx.x; t < 4096; t += 256) sphi[t] = phiL[t];
    if (threadIdx.x < 256) sWp[threadIdx.x] = WpL[threadIdx.x];
    if (threadIdx.x < 16) sbp[threadIdx.x] = bpL[threadIdx.x];
    const int lane = threadIdx.x & 63;
    const int wid = threadIdx.x >> 6;
    const int hlo = lane >> 3;
    const int pp = lane & 7;
    float wee[16], mlo[16], mhi[16];
#pragma unroll
    for (int k = 0; k < 16; k++) {
        wee[k] = WeeL[k * 64 + lane];
        mlo[k] = ML[k * 16 + hlo];
        mhi[k] = ML[k * 16 + 8 + hlo];
    }
    const float beev = beeL[lane];
    float gmx = 1.f, gax = 0.f;
    if (XBN) {
        const double mu = s2P[lane] * (1.0 / NN);
        const double var = q2P[lane] * (1.0 / NN) - mu * mu;
        const float inv = rsqrtf(fmaxf((float)var, 0.f) + 1e-5f);
        gmx = gnP[lane] * inv;
        gax = bnbP[lane] - (float)mu * gmx;
    }
    __syncthreads();
    for (int n = blockIdx.x * 4 + wid; n < NN; n += gridDim.x * 4) {
        float zd0, zd1;
        if (INM == 0) { zd0 = zd1 = pe[n * 8 + pp]; }
        else { float2 t = Z2[n * 64 + lane]; zd0 = t.x; zd1 = t.y; }
        float accx = XBN ? fmaxf(0.f, fmaf(bfc(Xh[n * 64 + lane]), gmx, gax))
                         : bfc(Xh[n * 64 + lane]);
        float az0 = zd0, az1 = zd1;
        int i0 = rowptr[n], i1 = rowptr[n + 1];
        if (i0 < 0) i0 = 0;
        if (i1 > EE) i1 = EE;
        for (int c = i0; c < i1; c += 64) {
            const int ce = (c + 64 < i1) ? c + 64 : i1;
            const int m = ce - c;
            const int mL = m - 1;
            int ci = c + lane; if (ci > i1 - 1) ci = i1 - 1;
            const u32 svec = sb[ci];
            u32 Aw, Bw, Nw, Mw;
            float Az0, Az1, Axs, Aea, Agl, Agh;
            float Bz0, Bz1, Bxs, Bea, Bgl, Bgh;
            float Nz0, Nz1, Nxs, Nea, Ngl, Ngh;
            float Mz0, Mz1, Mxs, Mea, Mgl, Mgh;
            EF(A, 0);
            EF(B, (1 > mL ? mL : 1));
            for (int k = 0; k < m; k += 2) {
                const int n0 = (k + 2 > mL) ? mL : k + 2;
                const int n1 = (k + 3 > mL) ? mL : k + 3;
                EF(N, n0);
                EF(M, n1);
                EC(A, 1.f);
                EC(B, (k + 1 <= mL) ? 1.f : 0.f);
                Aw = Nw; Az0 = Nz0; Az1 = Nz1; Axs = Nxs; Aea = Nea; Agl = Ngl; Agh = Ngh;
                Bw = Mw; Bz0 = Mz0; Bz1 = Mz1; Bxs = Mxs; Bea = Mea; Bgl = Mgl; Bgh = Mgh;
            }
        }
        Hf[n * 64 + lane] = accx;
        float r0 = sbp[hlo], r1 = sbp[8 + hlo];
#pragma unroll
        for (int h = 0; h < 8; h++) {
            const float v = __shfl(az0, (h << 3) + pp);
            r0 = fmaf(v, sWp[h * 16 + hlo], r0);
            r1 = fmaf(v, sWp[h * 16 + 8 + hlo], r1);
        }
#pragma unroll
        for (int h = 0; h < 8; h++) {
            const float v = __shfl(az1, (h << 3) + pp);
            r0 = fmaf(v, sWp[(8 + h) * 16 + hlo], r0);
            r1 = fmaf(v, sWp[(8 + h) * 16 + 8 + hlo], r1);
        }
        if (FIN) {
            outz[n * 128 + lane] = r0;
            outz[n * 128 + 64 + lane] = r1;
        } else {
            Z2O[n * 64 + lane] = make_float2(r0, r1);
        }
    }
}

// ==== SMALL-path fused edge pass (round-4, proven fallback) ====
template <int INM>
__global__ __launch_bounds__(256) void k_edge_s(const float* __restrict__ Zf,
                                                const float* __restrict__ pe,
                                                const float* __restrict__ Xf, const float* __restrict__ eat,
                                                const int* __restrict__ rowptr, const u32* __restrict__ sb,
                                                const int* __restrict__ eeo,
                                                const float* __restrict__ phiL, const float* __restrict__ WeeL,
                                                const float* __restrict__ beeL,
                                                const float* __restrict__ WgL, const float* __restrict__ bgL,
                                                const float* __restrict__ WpL, const float* __restrict__ bpL,
                                                float* __restrict__ Hf, float* __restrict__ ZfO,
                                                double* __restrict__ stats) {
    __shared__ float sphi[32 * 128];
    __shared__ float sWp[256];
    __shared__ float sbp[16];
    if (blockIdx.x == 0) stats[threadIdx.x] = 0.0;
    for (int t = threadIdx.x; t < 4096; t += 256) sphi[t] = phiL[t];
    if (threadIdx.x < 256) sWp[threadIdx.x] = WpL[threadIdx.x];
    if (threadIdx.x < 16) sbp[threadIdx.x] = bpL[threadIdx.x];
    const int lane = threadIdx.x & 63;
    const int wid = threadIdx.x >> 6;
    const int hlo = lane >> 3;
    const int pp = lane & 7;
    const int h16 = lane & 15;
    const int g16 = lane & 48;
    float wee[16], wgr[16];
#pragma unroll
    for (int k = 0; k < 16; k++) {
        wee[k] = WeeL[k * 64 + lane];
        wgr[k] = WgL[(g16 + k) * 16 + h16];
    }
    const float beev = beeL[lane];
    const float bgr = bgL[h16];
    __syncthreads();
    for (int n = blockIdx.x * 4 + wid; n < NN; n += gridDim.x * 4) {
        float zd0, zd1;
        if (INM == 0) { zd0 = zd1 = pe[n * 8 + pp]; }
        else { zd0 = Zf[n * 128 + lane]; zd1 = Zf[n * 128 + 64 + lane]; }
        float accx = Xf[n * 64 + lane];
        float az0 = zd0, az1 = zd1;
        int i0 = rowptr[n], i1 = rowptr[n + 1];
        if (i0 < 0) i0 = 0;
        if (i1 > EE) i1 = EE;
        for (int idx = i0; idx < i1; ++idx) {
            const u32 w = sb[idx];
            const int s = w & 0xffff;
            const int b = (w >> 16) & 31;
            int e = eeo[idx];
            e = (e < 0) ? 0 : ((e >= EE) ? EE - 1 : e);
            float zs0, zs1;
            if (INM == 0) { zs0 = zs1 = pe[s * 8 + pp]; }
            else { zs0 = Zf[s * 128 + lane]; zs1 = Zf[s * 128 + 64 + lane]; }
            float p0 = sphi[b * 128 + lane] * zs0 * zd0;
            float p1 = sphi[b * 128 + 64 + lane] * zs1 * zd1;
            p0 += __shfl_xor(p0, 1); p1 += __shfl_xor(p1, 1);
            p0 += __shfl_xor(p0, 2); p1 += __shfl_xor(p1, 2);
            p0 += __shfl_xor(p0, 4); p1 += __shfl_xor(p1, 4);
            float ea = beev + eat[(size_t)e * 64 + lane];
#pragma unroll
            for (int k = 0; k < 8; k++) ea = fmaf(lanebc(p0, k << 3), wee[k], ea);
#pragma unroll
            for (int k = 0; k < 8; k++) ea = fmaf(lanebc(p1, k << 3), wee[8 + k], ea);
            float gp = 0.f;
#pragma unroll
            for (int i = 0; i < 16; i++) gp = fmaf(__shfl(ea, g16 + i), wgr[i], gp);
            gp += __shfl_xor(gp, 16);
            gp += __shfl_xor(gp, 32);
            const float gv = fmaxf(gp + bgr, 0.f);
            const float glo = __shfl(gv, hlo);
            const float ghi = __shfl(gv, 8 + hlo);
            const float xs = Xf[s * 64 + lane];
            accx += fmaxf(0.f, xs + ea);
            az0 += fmaxf(0.f, zs0 + glo);
            az1 += fmaxf(0.f, zs1 + ghi);
        }
        Hf[n * 64 + lane] = accx;
        float r0 = sbp[hlo], r1 = sbp[8 + hlo];
#pragma unroll
        for (int h = 0; h < 8; h++) {
            const float v = __shfl(az0, (h << 3) + pp);
            r0 = fmaf(v, sWp[h * 16 + hlo], r0);
            r1 = fmaf(v, sWp[h * 16 + 8 + hlo], r1);
        }
#pragma unroll
        for (int h = 0; h < 8; h++) {
            const float v = __shfl(az1, (h << 3) + pp);
            r0 = fmaf(v, sWp[(8 + h) * 16 + hlo], r0);
            r1 = fmaf(v, sWp[(8 + h) * 16 + 8 + hlo], r1);
        }
        ZfO[n * 128 + lane] = r0;
        ZfO[n * 128 + 64 + lane] = r1;
    }
}

// ---- t = h @ W1 + b1 (in-place on Hf), fused BN1 stats ----
__global__ __launch_bounds__(256) void k_gemm1(float* Buf, const float* __restrict__ WL,
                                               const float* __restrict__ bL,
                                               double* __restrict__ sum, double* __restrict__ sq) {
    __shared__ float sW[4096];
    __shared__ double red[512];
    for (int t = threadIdx.x; t < 4096; t += 256) sW[t] = WL[t];
    const int lane = threadIdx.x & 63, wid = threadIdx.x >> 6;
    const float bv = bL[lane];
    __syncthreads();
    double s = 0.0, q = 0.0;
    for (int n = blockIdx.x * 4 + wid; n < NN; n += gridDim.x * 4) {
        const float h = Buf[n * 64 + lane];
        float a0 = bv, a1 = 0.f;
#pragma unroll
        for (int k = 0; k < 32; k++) a0 = fmaf(lanebc(h, k), sW[k * 64 + lane], a0);
#pragma unroll
        for (int k = 32; k < 64; k++) a1 = fmaf(lanebc(h, k), sW[k * 64 + lane], a1);
        const float acc = a0 + a1;
        Buf[n * 64 + lane] = acc;
        s += (double)acc;
        q += (double)acc * (double)acc;
    }
    red[threadIdx.x] = s;
    red[256 + threadIdx.x] = q;
    __syncthreads();
    if (threadIdx.x < 64) {
        s = red[threadIdx.x] + red[threadIdx.x + 64] + red[threadIdx.x + 128] + red[threadIdx.x + 192];
        q = red[256 + threadIdx.x] + red[320 + threadIdx.x] + red[384 + threadIdx.x] + red[448 + threadIdx.x];
        atomicAdd(&sum[lane], s);
        atomicAdd(&sq[lane], q);
    }
}

// ---- h2 = relu(BN1(t)) @ W2 + b2; out16: write raw-h2 bf16 to XhOut, else fp32 in-place ----
__global__ __launch_bounds__(256) void k_gemm2(float* Buf, const float* __restrict__ WL,
                                               const float* __restrict__ bL,
                                               const float* __restrict__ gL, const float* __restrict__ betaL,
                                               const double* __restrict__ s1, const double* __restrict__ q1,
                                               double* __restrict__ sum, double* __restrict__ sq,
                                               int out16, u16* __restrict__ XhOut) {
    __shared__ float sW[4096];
    __shared__ double red[512];
    for (int t = threadIdx.x; t < 4096; t += 256) sW[t] = WL[t];
    const int lane = threadIdx.x & 63, wid = threadIdx.x >> 6;
    const float bv = bL[lane];
    const double mu = s1[lane] * (1.0 / NN);
    const double var = q1[lane] * (1.0 / NN) - mu * mu;
    const float inv = rsqrtf(fmaxf((float)var, 0.f) + 1e-5f);
    const float gm = gL[lane] * inv;
    const float ga = betaL[lane] - (float)mu * gm;
    __syncthreads();
    double s = 0.0, q = 0.0;
    for (int n = blockIdx.x * 4 + wid; n < NN; n += gridDim.x * 4) {
        const float v = Buf[n * 64 + lane];
        const float r = fmaxf(fmaf(v, gm, ga), 0.f);
        float a0 = bv, a1 = 0.f;
#pragma unroll
        for (int k = 0; k < 32; k++) a0 = fmaf(lanebc(r, k), sW[k * 64 + lane], a0);
#pragma unroll
        for (int k = 32; k < 64; k++) a1 = fmaf(lanebc(r, k), sW[k * 64 + lane], a1);
        const float acc = a0 + a1;
        if (out16) XhOut[n * 64 + lane] = f2bf(acc);
        else Buf[n * 64 + lane] = acc;
        s += (double)acc;
        q += (double)acc * (double)acc;
    }
    red[threadIdx.x] = s;
    red[256 + threadIdx.x] = q;
    __syncthreads();
    if (threadIdx.x < 64) {
        s = red[threadIdx.x] + red[threadIdx.x + 64] + red[threadIdx.x + 128] + red[threadIdx.x + 192];
        q = red[256 + threadIdx.x] + red[320 + threadIdx.x] + red[384 + threadIdx.x] + red[448 + threadIdx.x];
        atomicAdd(&sum[lane], s);
        atomicAdd(&sq[lane], q);
    }
}

// ---- final (or small-path) bnout: x = BN2(h2) (+relu opt) ----
__global__ __launch_bounds__(256) void k_bnout(const float* __restrict__ In, float* __restrict__ Xf,
                                               const double* __restrict__ s2, const double* __restrict__ q2,
                                               const float* __restrict__ gL, const float* __restrict__ bL,
                                               int dorelu) {
    int i = blockIdx.x * 256 + threadIdx.x;
    const int f = i & 63;
    const double mu = s2[f] * (1.0 / NN);
    const double var = q2[f] * (1.0 / NN) - mu * mu;
    const float inv = rsqrtf(fmaxf((float)var, 0.f) + 1e-5f);
    const float gm = gL[f] * inv;
    const float ga = bL[f] - (float)mu * gm;
    for (; i < NN * 64; i += gridDim.x * 256) {
        float o = fmaf(In[i], gm, ga);
        if (dorelu) o = fmaxf(o, 0.f);
        Xf[i] = o;
    }
}

extern "C" void kernel_launch(void* const* d_in, const int* in_sizes, int n_in,
                              void* d_out, int out_size, void* d_ws, size_t ws_size,
                              hipStream_t stream) {
    (void)in_sizes; (void)n_in; (void)out_size;
    const float* x    = (const float*)d_in[0];
    const float* pe   = (const float*)d_in[1];
    const float* Lam  = (const float*)d_in[2];
    const float* eat  = (const float*)d_in[3];
    const int*   ei   = (const int*)d_in[4];
    const int*   batch= (const int*)d_in[5];
    const float* We1  = (const float*)d_in[6];
    const float* be1  = (const float*)d_in[7];
    const float* Wee  = (const float*)d_in[8];
    const float* bee  = (const float*)d_in[9];
    const float* W1   = (const float*)d_in[10];
    const float* b1   = (const float*)d_in[11];
    const float* g1   = (const float*)d_in[12];
    const float* bt1  = (const float*)d_in[13];
    const float* W2   = (const float*)d_in[14];
    const float* b2   = (const float*)d_in[15];
    const float* Wg   = (const float*)d_in[16];
    const float* bg   = (const float*)d_in[17];
    const float* Wp   = (const float*)d_in[18];
    const float* bp   = (const float*)d_in[19];
    const float* gn   = (const float*)d_in[20];
    const float* bnb  = (const float*)d_in[21];

    // output regions
    float* Xf   = (float*)d_out;              // [N,64] final x
    u16*   Xh   = (u16*)d_out;                // big path: bf16 x-state / raw-h2 in out-x region
    float* B    = (float*)d_out + 3200000;    // [N,128] z region

    // workspace layout
    float* A    = (float*)d_ws;                 // z plane [N][128] fp32, 25.6 MB
    float* Hf   = A + 6400000;
    float* MA   = Hf + 3200000;
    float* phiA = MA + 1024;
    double* stats = (double*)(phiA + 16384);    // LL*256 doubles (per-layer slots)
    int* rowptr = (int*)(stats + LL * 256);
    int* deg    = rowptr + NN + 1;
    int* bsum   = deg + NN;
    int* boff   = bsum + 256;
    int* cursor = boff + 256;
    u32* sb     = (u32*)(cursor + NN);          // EE
    int* eeo    = (int*)(sb + EE);              // EE
    u16* eatp   = (u16*)(eeo + EE);             // EE*64 u16 (64 MB)
    u32* EAGp   = (u32*)(eatp + (size_t)EE * 64); // EE*8 u32 per layer
    const size_t NEED_BIG  = (size_t)((char*)(EAGp + (size_t)EE * 8) - (char*)d_ws);
    const size_t NEED_BIG2 = (size_t)((char*)(EAGp + (size_t)EE * 32) - (char*)d_ws);
    const bool big2 = (ws_size >= NEED_BIG2);
    const bool big  = (ws_size >= NEED_BIG);

    float2* A2 = (float2*)A;
    float2* B2 = (float2*)B;

    const int NB_N = (NN + 255) / 256;
    const int NB_E = (EE + 255) / 256;

    k_init<<<1024, 256, 0, stream>>>(x, Xf, Xh, big ? 1 : 0, deg, cursor, stats);
    k_phi<<<LL * 32, 128, 0, stream>>>(Lam, We1, be1, phiA);
    k_hist<<<NB_E, 256, 0, stream>>>(ei, deg);
    k_scan1<<<NB_N, 256, 0, stream>>>(deg, rowptr, bsum);
    k_scan2<<<1, 256, 0, stream>>>(bsum, boff, rowptr, NB_N);
    k_scan3<<<NB_N, 256, 0, stream>>>(rowptr, boff);
    k_scatter<<<NB_E, 256, 0, stream>>>(ei, batch, rowptr, cursor, sb, eeo);
    if (big) {
        k_small<<<LL, 256, 0, stream>>>(Wee, Wg, MA);
        k_perm<<<4096, 256, 0, stream>>>(eat, eeo, eatp);
        if (big2)
            k_eag_all<<<NB_E, 256, 0, stream>>>(eatp, Wg, bee, bg, EAGp);
    }

    for (int l = 0; l < LL; l++) {
        const float* WeeL = Wee + l * 1024;
        const float* beeL = bee + l * 64;
        const float* WgL  = Wg + l * 1024;
        const float* bgL  = bg + l * 16;
        const float* WpL  = Wp + l * 256;
        const float* bpL  = bp + l * 16;
        const float* phiL = phiA + l * 4096;
        const float* ML   = MA + l * 256;
        double* sl = stats + l * 256;             // this layer's slot
        if (big) {
            const u32* EAGl = big2 ? (EAGp + (size_t)l * EE * 8) : EAGp;
            if (!big2)
                k_eag2<<<NB_E, 256, 0, stream>>>(eatp, WgL, beeL, bgL, EAGp);
            // BN-on-the-fly params come from PREVIOUS layer's slot
            const double* s2p = stats + (l - 1) * 256 + 128;
            const double* q2p = stats + (l - 1) * 256 + 192;
            const float* gnp  = gn + (l - 1) * 64;
            const float* bnbp = bnb + (l - 1) * 64;
            // z schedule: l0 pe->A2, l1 A2->B2, l2 B2->A2, l3 A2->B(final std layout)
            if (l == 0)
                k_edge2<0, 0, 0><<<6272, 256, 0, stream>>>(A2, pe, Xh, eatp, EAGl, rowptr, sb,
                                                           phiL, WeeL, beeL, ML, WpL, bpL,
                                                           Hf, A2, nullptr,
                                                           nullptr, nullptr, nullptr, nullptr);
            else if (l == 1)
                k_edge2<1, 0, 1><<<6272, 256, 0, stream>>>(A2, pe, Xh, eatp, EAGl, rowptr, sb,
                                                           phiL, WeeL, beeL, ML, WpL, bpL,
                                                           Hf, B2, nullptr,
                                                           gnp, bnbp, s2p, q2p);
            else if (l == 2)
                k_edge2<1, 0, 1><<<6272, 256, 0, stream>>>(B2, pe, Xh, eatp, EAGl, rowptr, sb,
                                                           phiL, WeeL, beeL, ML, WpL, bpL,
                                                           Hf, A2, nullptr,
                                                           gnp, bnbp, s2p, q2p);
            else
                k_edge2<1, 1, 1><<<6272, 256, 0, stream>>>(A2, pe, Xh, eatp, EAGl, rowptr, sb,
                                                           phiL, WeeL, beeL, ML, WpL, bpL,
                                                           Hf, nullptr, B,
                                                           gnp, bnbp, s2p, q2p);
            k_gemm1<<<512, 256, 0, stream>>>(Hf, W1 + l * 4096, b1 + l * 64, sl, sl + 64);
            k_gemm2<<<512, 256, 0, stream>>>(Hf, W2 + l * 4096, b2 + l * 64,
                                             g1 + l * 64, bt1 + l * 64, sl, sl + 64,
                                             sl + 128, sl + 192,
                                             (l < LL - 1) ? 1 : 0, Xh);
        } else {
            const float* Zin  = (l == 2) ? B : A;
            float*       Zout = (l == 1 || l == 3) ? B : A;
            if (l == 0)
                k_edge_s<0><<<2048, 256, 0, stream>>>(nullptr, pe, Xf, eat, rowptr, sb, eeo,
                                                      phiL, WeeL, beeL, WgL, bgL, WpL, bpL,
                                                      Hf, Zout, sl);
            else
                k_edge_s<1><<<2048, 256, 0, stream>>>(Zin, pe, Xf, eat, rowptr, sb, eeo,
                                                      phiL, WeeL, beeL, WgL, bgL, WpL, bpL,
                                                      Hf, Zout, sl);
            k_gemm1<<<512, 256, 0, stream>>>(Hf, W1 + l * 4096, b1 + l * 64, sl, sl + 64);
            k_gemm2<<<512, 256, 0, stream>>>(Hf, W2 + l * 4096, b2 + l * 64,
                                             g1 + l * 64, bt1 + l * 64, sl, sl + 64,
                                             sl + 128, sl + 192, 0, nullptr);
            k_bnout<<<1024, 256, 0, stream>>>(Hf, Xf, sl + 128, sl + 192,
                                              gn + l * 64, bnb + l * 64,
                                              (l == LL - 1) ? 0 : 1);
        }
    }
    if (big) {
        // final x output: BN2 of layer-3 raw h2 (fp32 in Hf), no relu
        double* sl3 = stats + (LL - 1) * 256;
        k_bnout<<<1024, 256, 0, stream>>>(Hf, Xf, sl3 + 128, sl3 + 192,
                                          gn + (LL - 1) * 64, bnb + (LL - 1) * 64, 0);
    }
}